// Round 17
// baseline (900.560 us; speedup 1.0000x reference)
//
#include <hip/hip_runtime.h>

#define MTOT 131072   // b*n
#define NB   65536    // n per batch
#define SNBINS 265302 // 2 * 51^3 sort bins
#define SNB_BLOCKS 1037  // ceil(SNBINS/256)

typedef __attribute__((ext_vector_type(8))) __bf16 bf16x8;
typedef __attribute__((ext_vector_type(4))) __bf16 bf16x4;
typedef __attribute__((ext_vector_type(4))) float  f32x4;

// ---------------------------------------------------------------- pmin
__global__ void pmin_init_kernel(float* pmin){
    if (threadIdx.x < 6) pmin[threadIdx.x] = 2.0f;   // p in [0,1)
}

__global__ void pmin_kernel(const float* __restrict__ p, float* __restrict__ pmin){
    int bi = blockIdx.y;
    float m0 = 2.f, m1 = 2.f, m2 = 2.f;
    for (int ni = blockIdx.x * blockDim.x + threadIdx.x; ni < NB; ni += gridDim.x * blockDim.x){
        const float* pp = p + ((size_t)bi * NB + ni) * 3;
        m0 = fminf(m0, pp[0]); m1 = fminf(m1, pp[1]); m2 = fminf(m2, pp[2]);
    }
    #pragma unroll
    for (int o = 32; o > 0; o >>= 1){
        m0 = fminf(m0, __shfl_down(m0, o, 64));
        m1 = fminf(m1, __shfl_down(m1, o, 64));
        m2 = fminf(m2, __shfl_down(m2, o, 64));
    }
    if ((threadIdx.x & 63) == 0){
        atomicMin((int*)(pmin + bi*3 + 0), __float_as_int(m0));
        atomicMin((int*)(pmin + bi*3 + 1), __float_as_int(m1));
        atomicMin((int*)(pmin + bi*3 + 2), __float_as_int(m2));
    }
}

// ---------------------------------------------------------------- spatial sort (locality permutation only)
__device__ __forceinline__ int sort_bin(const float* __restrict__ p, int m){
    int bi = m >> 16;
    int gx = (int)(p[m*3+0] * 51.0f); gx = gx > 50 ? 50 : gx;
    int gy = (int)(p[m*3+1] * 51.0f); gy = gy > 50 ? 50 : gy;
    int gz = (int)(p[m*3+2] * 51.0f); gz = gz > 50 ? 50 : gz;
    return bi * 132651 + (gx * 51 + gy) * 51 + gz;
}

__global__ void shist_kernel(const float* __restrict__ p, int* __restrict__ hist){
    int m = blockIdx.x * 256 + threadIdx.x;
    atomicAdd(hist + sort_bin(p, m), 1);
}

__global__ void sscan1_kernel(const int* __restrict__ hist, int* __restrict__ offs,
                              int* __restrict__ bsum){
    __shared__ int sh[256];
    int tid = threadIdx.x;
    int idx = blockIdx.x * 256 + tid;
    int v = (idx < SNBINS) ? hist[idx] : 0;
    sh[tid] = v;
    __syncthreads();
    #pragma unroll
    for (int off = 1; off < 256; off <<= 1){
        int t = (tid >= off) ? sh[tid - off] : 0;
        __syncthreads();
        sh[tid] += t;
        __syncthreads();
    }
    if (idx < SNBINS) offs[idx] = sh[tid] - v;
    if (tid == 255) bsum[blockIdx.x] = sh[255];
}

__global__ void sscan2_kernel(int* __restrict__ bsum){
    __shared__ int sh[256];
    int tid = threadIdx.x;
    const int CH = (SNB_BLOCKS + 255) / 256;
    int base = tid * CH, sum = 0;
    #pragma unroll
    for (int i = 0; i < CH; i++){
        int idx = base + i;
        if (idx < SNB_BLOCKS) sum += bsum[idx];
    }
    sh[tid] = sum;
    __syncthreads();
    #pragma unroll
    for (int off = 1; off < 256; off <<= 1){
        int t = (tid >= off) ? sh[tid - off] : 0;
        __syncthreads();
        sh[tid] += t;
        __syncthreads();
    }
    int run = (tid == 0) ? 0 : sh[tid - 1];
    #pragma unroll
    for (int i = 0; i < CH; i++){
        int idx = base + i;
        if (idx < SNB_BLOCKS){ int v = bsum[idx]; bsum[idx] = run; run += v; }
    }
}

__global__ void sscan3_kernel(int* __restrict__ offs, const int* __restrict__ bsum){
    int idx = blockIdx.x * 256 + threadIdx.x;
    if (idx < SNBINS) offs[idx] += bsum[blockIdx.x];
}

// scatter + sorted-p copy (ps[pos] = p[m]): downstream kernels read ps LINEARLY.
__global__ void sscatter_kernel(const float* __restrict__ p, int* __restrict__ offs,
                                int* __restrict__ sortpos, int* __restrict__ origid,
                                float* __restrict__ ps){
    int m = blockIdx.x * 256 + threadIdx.x;
    int pos = atomicAdd(offs + sort_bin(p, m), 1);
    sortpos[m] = pos;
    origid[pos] = m;
    ps[pos*3+0] = p[m*3+0];
    ps[pos*3+1] = p[m*3+1];
    ps[pos*3+2] = p[m*3+2];
}

// ---------------------------------------------------------------- voxel scatter (atomicMax of ids)
// f64 voxelization (floor(p/g) in double) matches the numpy f64 reference bit-exactly.
// Writes gcs in SORTED position with batch bit packed (bit 30): gcs[pos]=(bi<<30)|(gx<<20)|(gy<<10)|gz.
template<int USE_LDS>
__global__ void scatter_kernel(const float* __restrict__ p, const float* __restrict__ pmin,
                               const int* __restrict__ sortpos,
                               int* __restrict__ vgrid, int* __restrict__ gcs,
                               double gd, int D){
    extern __shared__ int lgrid[];
    int m  = blockIdx.x * blockDim.x + threadIdx.x;
    int bi = m >> 16;
    double px = (double)p[m*3], py = (double)p[m*3+1], pz = (double)p[m*3+2];
    int gx = (int)floor(px / gd) - (int)floor((double)pmin[bi*3+0] / gd);
    int gy = (int)floor(py / gd) - (int)floor((double)pmin[bi*3+1] / gd);
    int gz = (int)floor(pz / gd) - (int)floor((double)pmin[bi*3+2] / gd);
    int pos = sortpos ? sortpos[m] : m;
    gcs[pos] = (bi << 30) | (gx << 20) | (gy << 10) | gz;
    int cell = (gx * D + gy) * D + gz;

    if (!USE_LDS){
        atomicMax(vgrid + bi * D * D * D + cell, m);
        return;
    }
    int ncell = D * D * D;
    for (int c = threadIdx.x; c < ncell; c += 256) lgrid[c] = -1;
    __syncthreads();
    atomicMax(&lgrid[cell], m);
    __syncthreads();
    int* vg = vgrid + bi * ncell;
    for (int c = threadIdx.x; c < ncell; c += 256){
        int v = lgrid[c];
        if (v >= 0) atomicMax(vg + c, v);
    }
}

// translate vgrid entries (max-ORIGINAL-id reps, chosen already) to sorted ids, in place.
__global__ void vgtrans_kernel(int* __restrict__ vgrid, const int* __restrict__ sortpos, int NC2){
    int c = blockIdx.x * 256 + threadIdx.x;
    if (c >= NC2) return;
    int v = vgrid[c];
    if (v >= 0) vgrid[c] = sortpos[v];
}

// ---------------------------------------------------------------- 27-tap neighbor table (sorted space)
// gcs read LINEARLY; vgrid already holds sorted ids (post-vgtrans).
__global__ void nbr_kernel(const int* __restrict__ gcs, const int* __restrict__ vgrid,
                           int* __restrict__ nbr, int D){
    int s  = blockIdx.x * blockDim.x + threadIdx.x;
    int pk = gcs[s];
    int bi = (pk >> 30) & 1;
    int gx = (pk >> 20) & 1023, gy = (pk >> 10) & 1023, gz = pk & 1023;
    #pragma unroll
    for (int k = 0; k < 27; k++){
        int v;
        if (k == 13){
            v = s;
        } else {
            int x = gx + (k/9) - 1;
            int y = gy + ((k/3)%3) - 1;
            int z = gz + (k%3) - 1;
            if (x < 0 || y < 0 || z < 0 || x >= D || y >= D || z >= D) v = -1;
            else v = vgrid[((bi * D + x) * D + y) * D + z];
        }
        nbr[k * MTOT + s] = v;
    }
}

// ---------------------------------------------------------------- 27-tap neighbor table (per CELL; voxel scales)
__global__ void nbrv_kernel(const int* __restrict__ vgrid, int* __restrict__ nbrv,
                            int D, int NC2, int NC2pad){
    int ci = blockIdx.x * 256 + threadIdx.x;
    if (ci >= NC2pad) return;
    int D3 = D * D * D;
    int bi = (ci >= D3) ? 1 : 0;
    int r  = ci - bi * D3;
    int x = r / (D*D), y = (r / D) % D, z = r % D;
    #pragma unroll
    for (int k = 0; k < 27; k++){
        int v = -1;
        if (ci < NC2){
            int nx = x + (k/9) - 1;
            int ny = y + ((k/3)%3) - 1;
            int nz = z + (k%3) - 1;
            if (nx >= 0 && ny >= 0 && nz >= 0 && nx < D && ny < D && nz < D)
                v = vgrid[bi * D3 + ((nx * D + ny) * D + nz)];
        }
        nbrv[k * NC2pad + ci] = v;
    }
}

// ---------------------------------------------------------------- W_conv -> WAVE-LINEAR bf16 hi/lo planes (big path)
__global__ void wcv_wave_kernel(const float* __restrict__ w_conv,
                                __bf16* __restrict__ wth, __bf16* __restrict__ wtl){
    int o = blockIdx.x * 256 + threadIdx.x;          // 442368 total
    int cv = o / 27648, r = o % 27648;
    int k = r / 1024, q = r % 1024;
    int half = q >> 9, t = q & 511;
    int l = t >> 3, e = t & 7;
    int c = half*16 + (l & 15);
    int j = (l >> 4)*8 + e;
    float x = w_conv[cv*27648 + k*1024 + j*32 + c];
    __bf16 hi = (__bf16)x;
    wth[o] = hi;
    wtl[o] = (__bf16)(x - (float)hi);
}

// ---------------------------------------------------------------- W_conv -> [k][c][j] layout (fallback path)
__global__ void wcv_kernel(const float* __restrict__ w_conv,
                           __bf16* __restrict__ wth, __bf16* __restrict__ wtl){
    int o = blockIdx.x * 256 + threadIdx.x;          // 442368 total
    int cv = o / 27648, r = o % 27648;
    int k = r / 1024, q = r % 1024, c = q / 32, j = q % 32;
    float x = w_conv[cv*27648 + k*1024 + j*32 + c];
    __bf16 hi = (__bf16)x;
    wth[o] = hi;
    wtl[o] = (__bf16)(x - (float)hi);
}

// ---------------------------------------------------------------- w2 -> [kc][c(128)][j(32)] bf16 hi/lo
__global__ void w2t_kernel(const float* __restrict__ w2,
                           __bf16* __restrict__ w2th, __bf16* __restrict__ w2tl){
    int o = blockIdx.x * 256 + threadIdx.x;          // 32768 total
    int kc = o >> 12, r = o & 4095, c = r >> 5, j = r & 31;
    float x = w2[(kc*32 + j)*128 + c];
    __bf16 hi = (__bf16)x;
    w2th[o] = hi;
    w2tl[o] = (__bf16)(x - (float)hi);
}

// ---------------------------------------------------------------- fused mlp1 + per-scale mlp (pp = sorted or original p; linear)
__global__ void mlp_scale_kernel(const float* __restrict__ pp,
                                 const float* __restrict__ w1, const float* __restrict__ b1,
                                 const float* __restrict__ w, const float* __restrict__ b,
                                 __bf16* __restrict__ h0h, __bf16* __restrict__ h0l){
    int t = blockIdx.x * blockDim.x + threadIdx.x;
    int c = t & 31, s = t >> 5;
    float x = pp[s*3+0], y = pp[s*3+1], z = pp[s*3+2];
    float acc = b[c];
    #pragma unroll
    for (int j = 0; j < 32; j++){
        float ptsj = b1[j] + x * w1[j] + y * w1[32 + j] + z * w1[64 + j];
        acc += ptsj * w[j*32 + c];
    }
    __bf16 hi = (__bf16)acc;
    h0h[t] = hi;
    h0l[t] = (__bf16)(acc - (float)hi);
}

// ================================================================ BIG-WS PATH
// conv4 (scales 0-1): 4-way tap split + 2-stage pipeline + wave-linear W. Sorted space.
template<int MODE>
__global__ __launch_bounds__(256)
void conv4_kernel(const __bf16* __restrict__ fh, const __bf16* __restrict__ fl,
                  const __bf16* __restrict__ wth, const __bf16* __restrict__ wtl,
                  const float* __restrict__ bias, const int* __restrict__ nbr,
                  const __bf16* __restrict__ r2h, const __bf16* __restrict__ r2l,
                  __bf16* __restrict__ outh, __bf16* __restrict__ outl)
{
    __shared__ float buf0[32][33], buf1[32][33];
    int tid  = threadIdx.x;
    int lane = tid & 63, w = tid >> 6;
    int col  = lane & 15, kq = lane >> 4;
    int ptA  = blockIdx.x * 32 + col, ptB = ptA + 16;
    const int fragoff = kq * 8;

    f32x4 acc00, acc01, acc10, acc11;
    if (w == 0){
        float bv0 = bias[col], bv1 = bias[col + 16];
        acc00 = (f32x4){bv0,bv0,bv0,bv0}; acc01 = (f32x4){bv1,bv1,bv1,bv1};
        acc10 = (f32x4){bv0,bv0,bv0,bv0}; acc11 = (f32x4){bv1,bv1,bv1,bv1};
    } else {
        acc00 = (f32x4){0,0,0,0}; acc01 = (f32x4){0,0,0,0};
        acc10 = (f32x4){0,0,0,0}; acc11 = (f32x4){0,0,0,0};
    }

    int k0 = w * 7, k1 = (k0 + 7 < 27) ? k0 + 7 : 27;

    int idc = nbr[k0 * MTOT + ptA];
    int jdc = nbr[k0 * MTOT + ptB];
    int idn = (k0 + 1 < k1) ? nbr[(k0+1) * MTOT + ptA] : 0;
    int jdn = (k0 + 1 < k1) ? nbr[(k0+1) * MTOT + ptB] : 0;
    size_t oc0 = (size_t)(idc < 0 ? 0 : idc) * 32 + fragoff;
    size_t oc1 = (size_t)(jdc < 0 ? 0 : jdc) * 32 + fragoff;
    bf16x8 a0h = *(const bf16x8*)(fh + oc0);
    bf16x8 a0l = *(const bf16x8*)(fl + oc0);
    bf16x8 a1h = *(const bf16x8*)(fh + oc1);
    bf16x8 a1l = *(const bf16x8*)(fl + oc1);
    bool mc0 = idc < 0, mc1 = jdc < 0;

    #pragma unroll 1
    for (int k = k0; k < k1; k++){
        int idn2 = 0, jdn2 = 0;
        if (k + 2 < k1){ idn2 = nbr[(k+2) * MTOT + ptA]; jdn2 = nbr[(k+2) * MTOT + ptB]; }
        size_t on0 = (size_t)(idn < 0 ? 0 : idn) * 32 + fragoff;
        size_t on1 = (size_t)(jdn < 0 ? 0 : jdn) * 32 + fragoff;
        bf16x8 na0h = *(const bf16x8*)(fh + on0);
        bf16x8 na0l = *(const bf16x8*)(fl + on0);
        bf16x8 na1h = *(const bf16x8*)(fh + on1);
        bf16x8 na1l = *(const bf16x8*)(fl + on1);
        bool nm0 = idn < 0, nm1 = jdn < 0;

        const __bf16* wb = wth + (size_t)k*1024 + lane*8;
        const __bf16* wc = wtl + (size_t)k*1024 + lane*8;
        bf16x8 b0h = *(const bf16x8*)(wb);
        bf16x8 b1h = *(const bf16x8*)(wb + 512);
        bf16x8 b0l = *(const bf16x8*)(wc);
        bf16x8 b1l = *(const bf16x8*)(wc + 512);

        bf16x8 z = {};
        bf16x8 xa0h = mc0 ? z : a0h, xa0l = mc0 ? z : a0l;
        bf16x8 xa1h = mc1 ? z : a1h, xa1l = mc1 ? z : a1l;

        acc00 = __builtin_amdgcn_mfma_f32_16x16x32_bf16(xa0h, b0h, acc00, 0,0,0);
        acc00 = __builtin_amdgcn_mfma_f32_16x16x32_bf16(xa0h, b0l, acc00, 0,0,0);
        acc00 = __builtin_amdgcn_mfma_f32_16x16x32_bf16(xa0l, b0h, acc00, 0,0,0);
        acc01 = __builtin_amdgcn_mfma_f32_16x16x32_bf16(xa0h, b1h, acc01, 0,0,0);
        acc01 = __builtin_amdgcn_mfma_f32_16x16x32_bf16(xa0h, b1l, acc01, 0,0,0);
        acc01 = __builtin_amdgcn_mfma_f32_16x16x32_bf16(xa0l, b1h, acc01, 0,0,0);
        acc10 = __builtin_amdgcn_mfma_f32_16x16x32_bf16(xa1h, b0h, acc10, 0,0,0);
        acc10 = __builtin_amdgcn_mfma_f32_16x16x32_bf16(xa1h, b0l, acc10, 0,0,0);
        acc10 = __builtin_amdgcn_mfma_f32_16x16x32_bf16(xa1l, b0h, acc10, 0,0,0);
        acc11 = __builtin_amdgcn_mfma_f32_16x16x32_bf16(xa1h, b1h, acc11, 0,0,0);
        acc11 = __builtin_amdgcn_mfma_f32_16x16x32_bf16(xa1h, b1l, acc11, 0,0,0);
        acc11 = __builtin_amdgcn_mfma_f32_16x16x32_bf16(xa1l, b1h, acc11, 0,0,0);

        a0h = na0h; a0l = na0l; a1h = na1h; a1l = na1l;
        mc0 = nm0; mc1 = nm1; idn = idn2; jdn = jdn2;
    }

    if (w == 2){
        #pragma unroll
        for (int r = 0; r < 4; r++){
            buf0[kq*4 + r][col]           = acc00[r];
            buf0[kq*4 + r][col + 16]      = acc01[r];
            buf0[16 + kq*4 + r][col]      = acc10[r];
            buf0[16 + kq*4 + r][col + 16] = acc11[r];
        }
    } else if (w == 3){
        #pragma unroll
        for (int r = 0; r < 4; r++){
            buf1[kq*4 + r][col]           = acc00[r];
            buf1[kq*4 + r][col + 16]      = acc01[r];
            buf1[16 + kq*4 + r][col]      = acc10[r];
            buf1[16 + kq*4 + r][col + 16] = acc11[r];
        }
    }
    __syncthreads();
    if (w == 0){
        #pragma unroll
        for (int r = 0; r < 4; r++){
            acc00[r] += buf0[kq*4 + r][col];
            acc01[r] += buf0[kq*4 + r][col + 16];
            acc10[r] += buf0[16 + kq*4 + r][col];
            acc11[r] += buf0[16 + kq*4 + r][col + 16];
        }
    } else if (w == 1){
        #pragma unroll
        for (int r = 0; r < 4; r++){
            acc00[r] += buf1[kq*4 + r][col];
            acc01[r] += buf1[kq*4 + r][col + 16];
            acc10[r] += buf1[16 + kq*4 + r][col];
            acc11[r] += buf1[16 + kq*4 + r][col + 16];
        }
    }
    __syncthreads();
    if (w == 1){
        #pragma unroll
        for (int r = 0; r < 4; r++){
            buf1[kq*4 + r][col]           = acc00[r];
            buf1[kq*4 + r][col + 16]      = acc01[r];
            buf1[16 + kq*4 + r][col]      = acc10[r];
            buf1[16 + kq*4 + r][col + 16] = acc11[r];
        }
    }
    __syncthreads();
    if (w == 0){
        #pragma unroll
        for (int r = 0; r < 4; r++){
            buf0[kq*4 + r][col]           = acc00[r] + buf1[kq*4 + r][col];
            buf0[kq*4 + r][col + 16]      = acc01[r] + buf1[kq*4 + r][col + 16];
            buf0[16 + kq*4 + r][col]      = acc10[r] + buf1[16 + kq*4 + r][col];
            buf0[16 + kq*4 + r][col + 16] = acc11[r] + buf1[16 + kq*4 + r][col + 16];
        }
    }
    __syncthreads();

    int pt = tid >> 3, c0 = (tid & 7) * 4;
    size_t g = (size_t)(blockIdx.x * 32 + pt) * 32 + c0;
    bf16x4 rh = *(const bf16x4*)(fh + g);
    bf16x4 rl = *(const bf16x4*)(fl + g);
    bf16x4 oh4, ol4;
    if (MODE == 0){
        #pragma unroll
        for (int j = 0; j < 4; j++){
            float v = buf0[pt][c0 + j] + (float)rh[j] + (float)rl[j];
            __bf16 hi = (__bf16)v;
            oh4[j] = hi;
            ol4[j] = (__bf16)(v - (float)hi);
        }
    } else {
        bf16x4 sh = *(const bf16x4*)(r2h + g);
        bf16x4 sl = *(const bf16x4*)(r2l + g);
        #pragma unroll
        for (int j = 0; j < 4; j++){
            float v = buf0[pt][c0 + j] + (float)rh[j] + (float)rl[j]
                                       + (float)sh[j] + (float)sl[j];
            __bf16 hi = (__bf16)v;
            oh4[j] = hi;
            ol4[j] = (__bf16)(v - (float)hi);
        }
    }
    *(bf16x4*)(outh + g) = oh4;
    *(bf16x4*)(outl + g) = ol4;
}

// vconv: conv4 over CELLS, 26 taps (k=13 center handled per-point in combine).
__global__ __launch_bounds__(256)
void vconv_kernel(const __bf16* __restrict__ fh, const __bf16* __restrict__ fl,
                  const __bf16* __restrict__ wth, const __bf16* __restrict__ wtl,
                  const float* __restrict__ bias, const int* __restrict__ nbrv,
                  int NC2pad, float* __restrict__ vv)
{
    __shared__ float buf0[32][33], buf1[32][33];
    int tid  = threadIdx.x;
    int lane = tid & 63, w = tid >> 6;
    int col  = lane & 15, kq = lane >> 4;
    int ptA  = blockIdx.x * 32 + col, ptB = ptA + 16;
    const int fragoff = kq * 8;

    f32x4 acc00, acc01, acc10, acc11;
    if (w == 0){
        float bv0 = bias[col], bv1 = bias[col + 16];
        acc00 = (f32x4){bv0,bv0,bv0,bv0}; acc01 = (f32x4){bv1,bv1,bv1,bv1};
        acc10 = (f32x4){bv0,bv0,bv0,bv0}; acc11 = (f32x4){bv1,bv1,bv1,bv1};
    } else {
        acc00 = (f32x4){0,0,0,0}; acc01 = (f32x4){0,0,0,0};
        acc10 = (f32x4){0,0,0,0}; acc11 = (f32x4){0,0,0,0};
    }

    int k0 = (w == 0) ? 0 : (w == 1) ? 7 : (w == 2) ? 14 : 21;
    int k1 = (w == 0) ? 7 : (w == 1) ? 13 : (w == 2) ? 21 : 27;

    int idc = nbrv[k0 * NC2pad + ptA];
    int jdc = nbrv[k0 * NC2pad + ptB];
    int idn = (k0 + 1 < k1) ? nbrv[(k0+1) * NC2pad + ptA] : 0;
    int jdn = (k0 + 1 < k1) ? nbrv[(k0+1) * NC2pad + ptB] : 0;
    size_t oc0 = (size_t)(idc < 0 ? 0 : idc) * 32 + fragoff;
    size_t oc1 = (size_t)(jdc < 0 ? 0 : jdc) * 32 + fragoff;
    bf16x8 a0h = *(const bf16x8*)(fh + oc0);
    bf16x8 a0l = *(const bf16x8*)(fl + oc0);
    bf16x8 a1h = *(const bf16x8*)(fh + oc1);
    bf16x8 a1l = *(const bf16x8*)(fl + oc1);
    bool mc0 = idc < 0, mc1 = jdc < 0;

    #pragma unroll 1
    for (int k = k0; k < k1; k++){
        int idn2 = 0, jdn2 = 0;
        if (k + 2 < k1){ idn2 = nbrv[(k+2) * NC2pad + ptA]; jdn2 = nbrv[(k+2) * NC2pad + ptB]; }
        size_t on0 = (size_t)(idn < 0 ? 0 : idn) * 32 + fragoff;
        size_t on1 = (size_t)(jdn < 0 ? 0 : jdn) * 32 + fragoff;
        bf16x8 na0h = *(const bf16x8*)(fh + on0);
        bf16x8 na0l = *(const bf16x8*)(fl + on0);
        bf16x8 na1h = *(const bf16x8*)(fh + on1);
        bf16x8 na1l = *(const bf16x8*)(fl + on1);
        bool nm0 = idn < 0, nm1 = jdn < 0;

        const __bf16* wb = wth + (size_t)k*1024 + lane*8;
        const __bf16* wc = wtl + (size_t)k*1024 + lane*8;
        bf16x8 b0h = *(const bf16x8*)(wb);
        bf16x8 b1h = *(const bf16x8*)(wb + 512);
        bf16x8 b0l = *(const bf16x8*)(wc);
        bf16x8 b1l = *(const bf16x8*)(wc + 512);

        bf16x8 z = {};
        bf16x8 xa0h = mc0 ? z : a0h, xa0l = mc0 ? z : a0l;
        bf16x8 xa1h = mc1 ? z : a1h, xa1l = mc1 ? z : a1l;

        acc00 = __builtin_amdgcn_mfma_f32_16x16x32_bf16(xa0h, b0h, acc00, 0,0,0);
        acc00 = __builtin_amdgcn_mfma_f32_16x16x32_bf16(xa0h, b0l, acc00, 0,0,0);
        acc00 = __builtin_amdgcn_mfma_f32_16x16x32_bf16(xa0l, b0h, acc00, 0,0,0);
        acc01 = __builtin_amdgcn_mfma_f32_16x16x32_bf16(xa0h, b1h, acc01, 0,0,0);
        acc01 = __builtin_amdgcn_mfma_f32_16x16x32_bf16(xa0h, b1l, acc01, 0,0,0);
        acc01 = __builtin_amdgcn_mfma_f32_16x16x32_bf16(xa0l, b1h, acc01, 0,0,0);
        acc10 = __builtin_amdgcn_mfma_f32_16x16x32_bf16(xa1h, b0h, acc10, 0,0,0);
        acc10 = __builtin_amdgcn_mfma_f32_16x16x32_bf16(xa1h, b0l, acc10, 0,0,0);
        acc10 = __builtin_amdgcn_mfma_f32_16x16x32_bf16(xa1l, b0h, acc10, 0,0,0);
        acc11 = __builtin_amdgcn_mfma_f32_16x16x32_bf16(xa1h, b1h, acc11, 0,0,0);
        acc11 = __builtin_amdgcn_mfma_f32_16x16x32_bf16(xa1h, b1l, acc11, 0,0,0);
        acc11 = __builtin_amdgcn_mfma_f32_16x16x32_bf16(xa1l, b1h, acc11, 0,0,0);

        a0h = na0h; a0l = na0l; a1h = na1h; a1l = na1l;
        mc0 = nm0; mc1 = nm1; idn = idn2; jdn = jdn2;
    }

    if (w == 2){
        #pragma unroll
        for (int r = 0; r < 4; r++){
            buf0[kq*4 + r][col]           = acc00[r];
            buf0[kq*4 + r][col + 16]      = acc01[r];
            buf0[16 + kq*4 + r][col]      = acc10[r];
            buf0[16 + kq*4 + r][col + 16] = acc11[r];
        }
    } else if (w == 3){
        #pragma unroll
        for (int r = 0; r < 4; r++){
            buf1[kq*4 + r][col]           = acc00[r];
            buf1[kq*4 + r][col + 16]      = acc01[r];
            buf1[16 + kq*4 + r][col]      = acc10[r];
            buf1[16 + kq*4 + r][col + 16] = acc11[r];
        }
    }
    __syncthreads();
    if (w == 0){
        #pragma unroll
        for (int r = 0; r < 4; r++){
            acc00[r] += buf0[kq*4 + r][col];
            acc01[r] += buf0[kq*4 + r][col + 16];
            acc10[r] += buf0[16 + kq*4 + r][col];
            acc11[r] += buf0[16 + kq*4 + r][col + 16];
        }
    } else if (w == 1){
        #pragma unroll
        for (int r = 0; r < 4; r++){
            acc00[r] += buf1[kq*4 + r][col];
            acc01[r] += buf1[kq*4 + r][col + 16];
            acc10[r] += buf1[16 + kq*4 + r][col];
            acc11[r] += buf1[16 + kq*4 + r][col + 16];
        }
    }
    __syncthreads();
    if (w == 1){
        #pragma unroll
        for (int r = 0; r < 4; r++){
            buf1[kq*4 + r][col]           = acc00[r];
            buf1[kq*4 + r][col + 16]      = acc01[r];
            buf1[16 + kq*4 + r][col]      = acc10[r];
            buf1[16 + kq*4 + r][col + 16] = acc11[r];
        }
    }
    __syncthreads();
    if (w == 0){
        #pragma unroll
        for (int r = 0; r < 4; r++){
            buf0[kq*4 + r][col]           = acc00[r] + buf1[kq*4 + r][col];
            buf0[kq*4 + r][col + 16]      = acc01[r] + buf1[kq*4 + r][col + 16];
            buf0[16 + kq*4 + r][col]      = acc10[r] + buf1[16 + kq*4 + r][col];
            buf0[16 + kq*4 + r][col + 16] = acc11[r] + buf1[16 + kq*4 + r][col + 16];
        }
    }
    __syncthreads();

    int pt = tid >> 3, c0 = (tid & 7) * 4;
    float* o = vv + (size_t)(blockIdx.x * 32 + pt) * 32 + c0;
    ((float4*)o)[0] = make_float4(buf0[pt][c0], buf0[pt][c0+1], buf0[pt][c0+2], buf0[pt][c0+3]);
}

// combine: per-point center term + voxel-conv gather + residual(s). All sorted/linear except vv gather.
template<int MODE>
__global__ __launch_bounds__(256)
void combine_kernel(const __bf16* __restrict__ fh, const __bf16* __restrict__ fl,
                    const __bf16* __restrict__ wth, const __bf16* __restrict__ wtl,
                    const float* __restrict__ vv, const int* __restrict__ gcs, int D,
                    const __bf16* __restrict__ r2h, const __bf16* __restrict__ r2l,
                    __bf16* __restrict__ outh, __bf16* __restrict__ outl)
{
    __shared__ float vsh[128][33];
    int tid  = threadIdx.x;
    int lane = tid & 63, w = tid >> 6;
    int col  = lane & 15, kq = lane >> 4;
    const int fragoff = kq * 8;
    int mB  = blockIdx.x * 128 + w * 32;
    int ptA = mB + col, ptB = ptA + 16;

    size_t oA = (size_t)ptA * 32 + fragoff;
    size_t oB = (size_t)ptB * 32 + fragoff;
    bf16x8 a0h = *(const bf16x8*)(fh + oA);
    bf16x8 a0l = *(const bf16x8*)(fl + oA);
    bf16x8 a1h = *(const bf16x8*)(fh + oB);
    bf16x8 a1l = *(const bf16x8*)(fl + oB);

    const __bf16* wb = wth + 13*1024 + lane*8;
    const __bf16* wc = wtl + 13*1024 + lane*8;
    bf16x8 b0h = *(const bf16x8*)(wb);
    bf16x8 b1h = *(const bf16x8*)(wb + 512);
    bf16x8 b0l = *(const bf16x8*)(wc);
    bf16x8 b1l = *(const bf16x8*)(wc + 512);

    f32x4 acc00 = {0,0,0,0}, acc01 = {0,0,0,0}, acc10 = {0,0,0,0}, acc11 = {0,0,0,0};
    acc00 = __builtin_amdgcn_mfma_f32_16x16x32_bf16(a0h, b0h, acc00, 0,0,0);
    acc00 = __builtin_amdgcn_mfma_f32_16x16x32_bf16(a0h, b0l, acc00, 0,0,0);
    acc00 = __builtin_amdgcn_mfma_f32_16x16x32_bf16(a0l, b0h, acc00, 0,0,0);
    acc01 = __builtin_amdgcn_mfma_f32_16x16x32_bf16(a0h, b1h, acc01, 0,0,0);
    acc01 = __builtin_amdgcn_mfma_f32_16x16x32_bf16(a0h, b1l, acc01, 0,0,0);
    acc01 = __builtin_amdgcn_mfma_f32_16x16x32_bf16(a0l, b1h, acc01, 0,0,0);
    acc10 = __builtin_amdgcn_mfma_f32_16x16x32_bf16(a1h, b0h, acc10, 0,0,0);
    acc10 = __builtin_amdgcn_mfma_f32_16x16x32_bf16(a1h, b0l, acc10, 0,0,0);
    acc10 = __builtin_amdgcn_mfma_f32_16x16x32_bf16(a1l, b0h, acc10, 0,0,0);
    acc11 = __builtin_amdgcn_mfma_f32_16x16x32_bf16(a1h, b1h, acc11, 0,0,0);
    acc11 = __builtin_amdgcn_mfma_f32_16x16x32_bf16(a1h, b1l, acc11, 0,0,0);
    acc11 = __builtin_amdgcn_mfma_f32_16x16x32_bf16(a1l, b1h, acc11, 0,0,0);

    #pragma unroll
    for (int r = 0; r < 4; r++){
        vsh[w*32 + kq*4 + r][col]           = acc00[r];
        vsh[w*32 + kq*4 + r][col + 16]      = acc01[r];
        vsh[w*32 + 16 + kq*4 + r][col]      = acc10[r];
        vsh[w*32 + 16 + kq*4 + r][col + 16] = acc11[r];
    }
    __syncthreads();

    int pt = tid >> 1, c0 = (tid & 1) * 16;
    int s  = blockIdx.x * 128 + pt;
    int pk = gcs[s];
    int bi = (pk >> 30) & 1;
    int gx = (pk >> 20) & 1023, gy = (pk >> 10) & 1023, gz = pk & 1023;
    int ci = ((bi * D + gx) * D + gy) * D + gz;

    const float* vrow = vv + (size_t)ci * 32 + c0;
    size_t g = (size_t)s * 32 + c0;
    bf16x8 rh0 = *(const bf16x8*)(fh + g);
    bf16x8 rh1 = *(const bf16x8*)(fh + g + 8);
    bf16x8 rl0 = *(const bf16x8*)(fl + g);
    bf16x8 rl1 = *(const bf16x8*)(fl + g + 8);
    bf16x8 sh0, sh1, sl0, sl1;
    if (MODE == 1){
        sh0 = *(const bf16x8*)(r2h + g);
        sh1 = *(const bf16x8*)(r2h + g + 8);
        sl0 = *(const bf16x8*)(r2l + g);
        sl1 = *(const bf16x8*)(r2l + g + 8);
    }
    bf16x8 oh0, oh1, ol0, ol1;
    #pragma unroll
    for (int j = 0; j < 8; j++){
        float v = vsh[pt][c0 + j] + vrow[j] + (float)rh0[j] + (float)rl0[j];
        if (MODE == 1) v += (float)sh0[j] + (float)sl0[j];
        __bf16 hi = (__bf16)v;
        oh0[j] = hi; ol0[j] = (__bf16)(v - (float)hi);
    }
    #pragma unroll
    for (int j = 0; j < 8; j++){
        float v = vsh[pt][c0 + 8 + j] + vrow[8 + j] + (float)rh1[j] + (float)rl1[j];
        if (MODE == 1) v += (float)sh1[j] + (float)sl1[j];
        __bf16 hi = (__bf16)v;
        oh1[j] = hi; ol1[j] = (__bf16)(v - (float)hi);
    }
    *(bf16x8*)(outh + g)     = oh0;
    *(bf16x8*)(outh + g + 8) = oh1;
    *(bf16x8*)(outl + g)     = ol0;
    *(bf16x8*)(outl + g + 8) = ol1;
}

// mlp2: 16 pts/wave (8192 waves -> 100% occ ceiling; r16 was 4096 waves, 17% occ,
// 2.3 TB/s BW-latency-bound at 58 us). Per-output MFMA order unchanged -> bitwise-same.
__global__ __launch_bounds__(256)
void mlp2_kernel(const __bf16* __restrict__ vplanes,
                 const __bf16* __restrict__ w2th, const __bf16* __restrict__ w2tl,
                 const float* __restrict__ b2, const int* __restrict__ origid,
                 float* __restrict__ out)
{
    int tid  = threadIdx.x;
    int lane = tid & 63, w = tid >> 6;
    int col  = lane & 15, kq = lane >> 4;
    const int fragoff = kq * 8;
    int pbase = blockIdx.x * 64 + w * 16;
    size_t oA = (size_t)(pbase + col) * 32 + fragoff;

    f32x4 acc[4][2];
    #pragma unroll
    for (int s = 0; s < 4; s++){
        acc[s][0] = (f32x4){0,0,0,0};
        acc[s][1] = (f32x4){0,0,0,0};
    }

    bf16x8 a0h = *(const bf16x8*)(vplanes + oA);
    bf16x8 a0l = *(const bf16x8*)(vplanes + 4194304 + oA);

    #pragma unroll 1
    for (int kc = 0; kc < 8; kc++){
        bf16x8 na0h, na0l;
        if (kc < 7){
            const __bf16* fnh = vplanes + (size_t)(kc+1) * 8388608;
            na0h = *(const bf16x8*)(fnh + oA);
            na0l = *(const bf16x8*)(fnh + 4194304 + oA);
        } else { na0h = a0h; na0l = a0l; }

        const __bf16* wbase  = w2th + (size_t)kc * 4096;
        const __bf16* wlbase = w2tl + (size_t)kc * 4096;
        #pragma unroll
        for (int s = 0; s < 4; s++){
            const __bf16* wb = wbase  + (s*32 + col) * 32 + fragoff;
            const __bf16* wc = wlbase + (s*32 + col) * 32 + fragoff;
            bf16x8 b0h = *(const bf16x8*)(wb);
            bf16x8 b1h = *(const bf16x8*)(wb + 512);
            bf16x8 b0l = *(const bf16x8*)(wc);
            bf16x8 b1l = *(const bf16x8*)(wc + 512);

            acc[s][0] = __builtin_amdgcn_mfma_f32_16x16x32_bf16(a0h, b0h, acc[s][0], 0,0,0);
            acc[s][0] = __builtin_amdgcn_mfma_f32_16x16x32_bf16(a0h, b0l, acc[s][0], 0,0,0);
            acc[s][0] = __builtin_amdgcn_mfma_f32_16x16x32_bf16(a0l, b0h, acc[s][0], 0,0,0);
            acc[s][1] = __builtin_amdgcn_mfma_f32_16x16x32_bf16(a0h, b1h, acc[s][1], 0,0,0);
            acc[s][1] = __builtin_amdgcn_mfma_f32_16x16x32_bf16(a0h, b1l, acc[s][1], 0,0,0);
            acc[s][1] = __builtin_amdgcn_mfma_f32_16x16x32_bf16(a0l, b1h, acc[s][1], 0,0,0);
        }

        a0h = na0h; a0l = na0l;
    }

    #pragma unroll
    for (int s = 0; s < 4; s++){
        float bl = b2[s*32 + col], bh = b2[s*32 + 16 + col];
        #pragma unroll
        for (int r = 0; r < 4; r++){
            int iA = pbase + kq*4 + r;
            size_t rowA = (size_t)(origid ? origid[iA] : iA) * 128;
            out[rowA + s*32 + col]      = acc[s][0][r] + bl;
            out[rowA + s*32 + 16 + col] = acc[s][1][r] + bh;
        }
    }
}

// ================================================================ FALLBACK PATH (round-9 structure; old W layout)
template<int MODE>
__global__ __launch_bounds__(256)
void conv_mfma_kernel(const __bf16* __restrict__ fh, const __bf16* __restrict__ fl,
                      const __bf16* __restrict__ wth, const __bf16* __restrict__ wtl,
                      const float* __restrict__ bias, const int* __restrict__ nbr,
                      const __bf16* __restrict__ r2h, const __bf16* __restrict__ r2l,
                      const float* __restrict__ w2i, const float* __restrict__ b2,
                      __bf16* __restrict__ outh, __bf16* __restrict__ outl,
                      float* __restrict__ out)
{
    __shared__ float vsh[64][33];
    int tid  = threadIdx.x;
    int lane = tid & 63, wid = tid >> 6;
    int pair = wid >> 1;
    int half = wid & 1;
    int col  = lane & 15, kq = lane >> 4;
    int m0   = blockIdx.x * 64 + pair * 32;
    int ptA  = m0 + col, ptB = ptA + 16;
    const int fragoff = kq * 8;

    f32x4 acc00, acc01, acc10, acc11;
    if (half == 0){
        float bv0 = bias[col], bv1 = bias[col + 16];
        acc00 = (f32x4){bv0,bv0,bv0,bv0}; acc01 = (f32x4){bv1,bv1,bv1,bv1};
        acc10 = (f32x4){bv0,bv0,bv0,bv0}; acc11 = (f32x4){bv1,bv1,bv1,bv1};
    } else {
        acc00 = (f32x4){0,0,0,0}; acc01 = (f32x4){0,0,0,0};
        acc10 = (f32x4){0,0,0,0}; acc11 = (f32x4){0,0,0,0};
    }

    int k0 = half ? 14 : 0;
    int k1 = half ? 27 : 14;
    #pragma unroll 1
    for (int k = k0; k < k1; k++){
        int nb0 = nbr[k * MTOT + ptA];
        int nb1 = nbr[k * MTOT + ptB];
        size_t o0 = (size_t)(nb0 < 0 ? 0 : nb0) * 32 + fragoff;
        size_t o1 = (size_t)(nb1 < 0 ? 0 : nb1) * 32 + fragoff;
        bf16x8 a0h = *(const bf16x8*)(fh + o0);
        bf16x8 a0l = *(const bf16x8*)(fl + o0);
        bf16x8 a1h = *(const bf16x8*)(fh + o1);
        bf16x8 a1l = *(const bf16x8*)(fl + o1);
        bf16x8 z = {};
        if (nb0 < 0){ a0h = z; a0l = z; }
        if (nb1 < 0){ a1h = z; a1l = z; }

        const __bf16* wb = wth + (size_t)k*1024 + col*32 + fragoff;
        const __bf16* wc = wtl + (size_t)k*1024 + col*32 + fragoff;
        bf16x8 b0h = *(const bf16x8*)(wb);
        bf16x8 b1h = *(const bf16x8*)(wb + 512);
        bf16x8 b0l = *(const bf16x8*)(wc);
        bf16x8 b1l = *(const bf16x8*)(wc + 512);

        acc00 = __builtin_amdgcn_mfma_f32_16x16x32_bf16(a0h, b0h, acc00, 0,0,0);
        acc00 = __builtin_amdgcn_mfma_f32_16x16x32_bf16(a0h, b0l, acc00, 0,0,0);
        acc00 = __builtin_amdgcn_mfma_f32_16x16x32_bf16(a0l, b0h, acc00, 0,0,0);
        acc01 = __builtin_amdgcn_mfma_f32_16x16x32_bf16(a0h, b1h, acc01, 0,0,0);
        acc01 = __builtin_amdgcn_mfma_f32_16x16x32_bf16(a0h, b1l, acc01, 0,0,0);
        acc01 = __builtin_amdgcn_mfma_f32_16x16x32_bf16(a0l, b1h, acc01, 0,0,0);
        acc10 = __builtin_amdgcn_mfma_f32_16x16x32_bf16(a1h, b0h, acc10, 0,0,0);
        acc10 = __builtin_amdgcn_mfma_f32_16x16x32_bf16(a1h, b0l, acc10, 0,0,0);
        acc10 = __builtin_amdgcn_mfma_f32_16x16x32_bf16(a1l, b0h, acc10, 0,0,0);
        acc11 = __builtin_amdgcn_mfma_f32_16x16x32_bf16(a1h, b1h, acc11, 0,0,0);
        acc11 = __builtin_amdgcn_mfma_f32_16x16x32_bf16(a1h, b1l, acc11, 0,0,0);
        acc11 = __builtin_amdgcn_mfma_f32_16x16x32_bf16(a1l, b1h, acc11, 0,0,0);
    }

    if (half == 1){
        #pragma unroll
        for (int r = 0; r < 4; r++){
            vsh[pair*32 + kq*4 + r][col]           = acc00[r];
            vsh[pair*32 + kq*4 + r][col + 16]      = acc01[r];
            vsh[pair*32 + 16 + kq*4 + r][col]      = acc10[r];
            vsh[pair*32 + 16 + kq*4 + r][col + 16] = acc11[r];
        }
    }
    __syncthreads();
    if (half == 0){
        #pragma unroll
        for (int r = 0; r < 4; r++){
            vsh[pair*32 + kq*4 + r][col]           += acc00[r];
            vsh[pair*32 + kq*4 + r][col + 16]      += acc01[r];
            vsh[pair*32 + 16 + kq*4 + r][col]      += acc10[r];
            vsh[pair*32 + 16 + kq*4 + r][col + 16] += acc11[r];
        }
    }
    __syncthreads();

    if (MODE == 0){
        int eidx = tid * 8;
        int pt = eidx >> 5, c0 = eidx & 31;
        size_t g = (size_t)blockIdx.x * 2048 + eidx;
        bf16x8 rh = *(const bf16x8*)(fh + g);
        bf16x8 rl = *(const bf16x8*)(fl + g);
        bf16x8 oh8, ol8;
        #pragma unroll
        for (int j = 0; j < 8; j++){
            float v = vsh[pt][c0 + j] + (float)rh[j] + (float)rl[j];
            __bf16 hi = (__bf16)v;
            oh8[j] = hi;
            ol8[j] = (__bf16)(v - (float)hi);
        }
        *(bf16x8*)(outh + g) = oh8;
        *(bf16x8*)(outl + g) = ol8;
    } else {
        int eidx = tid * 8;
        int pt = eidx >> 5, c0 = eidx & 31;
        size_t g = (size_t)blockIdx.x * 2048 + eidx;
        bf16x8 rh = *(const bf16x8*)(fh + g);
        bf16x8 rl = *(const bf16x8*)(fl + g);
        bf16x8 sh = *(const bf16x8*)(r2h + g);
        bf16x8 sl = *(const bf16x8*)(r2l + g);
        #pragma unroll
        for (int j = 0; j < 8; j++)
            vsh[pt][c0 + j] += (float)rh[j] + (float)rl[j] + (float)sh[j] + (float)sl[j];
        __syncthreads();

        int pm = tid & 63;
        int tg = __builtin_amdgcn_readfirstlane(tid >> 6);
        size_t m = (size_t)blockIdx.x * 64 + pm;
        float o32[32];
        float* obase = out + m*128 + tg*32;
        if (MODE == 2){
            #pragma unroll
            for (int o = 0; o < 32; o++) o32[o] = b2[tg*32 + o];
        } else {
            #pragma unroll
            for (int q = 0; q < 8; q++){
                float4 t4 = ((const float4*)obase)[q];
                o32[q*4+0] = t4.x; o32[q*4+1] = t4.y; o32[q*4+2] = t4.z; o32[q*4+3] = t4.w;
            }
        }
        #pragma unroll
        for (int c = 0; c < 32; c++){
            float vc = vsh[pm][c];
            const float* w2r = w2i + c*128 + tg*32;
            #pragma unroll
            for (int o = 0; o < 32; o++) o32[o] += vc * w2r[o];
        }
        #pragma unroll
        for (int q = 0; q < 8; q++)
            ((float4*)obase)[q] = make_float4(o32[q*4+0], o32[q*4+1], o32[q*4+2], o32[q*4+3]);
    }
}

// ---------------------------------------------------------------- launch
extern "C" void kernel_launch(void* const* d_in, const int* in_sizes, int n_in,
                              void* d_out, int out_size, void* d_ws, size_t ws_size,
                              hipStream_t stream)
{
    static const int want[9] = {393216, 96, 32, 8192, 256, 442368, 512, 32768, 128};
    const void* bound[9];
    for (int i = 0; i < 9; i++) bound[i] = d_in[i];
    if (n_in == 9){
        for (int i = 0; i < 9; i++)
            for (int j = 0; j < 9; j++)
                if (in_sizes[j] == want[i]) { bound[i] = d_in[j]; break; }
    }
    const float* p      = (const float*)bound[0];
    const float* w1     = (const float*)bound[1];
    const float* b1     = (const float*)bound[2];
    const float* w_mlp  = (const float*)bound[3];
    const float* b_mlp  = (const float*)bound[4];
    const float* w_conv = (const float*)bound[5];
    const float* b_conv = (const float*)bound[6];
    const float* w2     = (const float*)bound[7];
    const float* b2     = (const float*)bound[8];
    float* out = (float*)d_out;

    char* ws = (char*)d_ws;
    __bf16* h0h  = (__bf16*)(ws);
    __bf16* h0l  = (__bf16*)(ws + 8388608);
    __bf16* h1h  = (__bf16*)(ws + 16777216);
    int*    vgrid= (int*)   (ws + 16777216);            // alias of h1h (dead before h1h written)
    __bf16* h1l  = (__bf16*)(ws + 25165824);
    int*    nbr  = (int*)   (ws + 33554432);            // 14,155,776 B (per-point nbr OR nbrv+vv)
    int*    nbrv = (int*)   (ws + 33554432);
    float*  vv   = (float*) (ws + 33554432 + 6291456);
    __bf16* wth  = (__bf16*)(ws + 47710208);            // 884,736 B
    __bf16* wtl  = (__bf16*)(ws + 48594944);            // 884,736 B
    __bf16* w2th = (__bf16*)(ws + 49479680);            // 65,536 B
    __bf16* w2tl = (__bf16*)(ws + 49545216);            // 65,536 B
    float*  pmin = (float*) (ws + 49610752);            // 256 B
    int*    gcs  = (int*)   (ws + 49612800);            // 524,288 B (sorted-space gc, bi in bit30)
    __bf16* vpl  = (__bf16*)(ws + 50331648);            // 8 x 16 MiB v planes -> ends 184,549,376
    int*    hist = (int*)   (ws + 184549376);           // 1,064,960 B
    int*    offs = (int*)   (ws + 185614336);           // 1,064,960 B
    int*    sortpos=(int*)  (ws + 186679296);           // 524,288 B
    int*    origid =(int*)  (ws + 187203584);           // 524,288 B
    int*    bsum   =(int*)  (ws + 187727872);           // 8,192 B
    float*  ps     =(float*)(ws + 187736064);           // 1,572,864 B -> ends 189,308,928

    const bool big = (ws_size >= 184549376ULL);
    const bool srt = (ws_size >= 189308928ULL);
    const int* oid = srt ? origid  : nullptr;
    const int* spp = srt ? sortpos : nullptr;
    const float* pp = srt ? ps : p;                      // linear per-point coords source

    static const double GS[8] = {0.01, 0.02, 0.04, 0.08, 0.16, 0.32, 0.64, 1.28};
    static const int    DS[8] = {101, 51, 26, 14, 8, 5, 3, 2};   // ceil(1/g)+1

    pmin_init_kernel<<<1, 64, 0, stream>>>(pmin);
    pmin_kernel<<<dim3(64, 2), 256, 0, stream>>>(p, pmin);
    if (big){
        wcv_wave_kernel<<<1728, 256, 0, stream>>>(w_conv, wth, wtl);
        w2t_kernel<<<128, 256, 0, stream>>>(w2, w2th, w2tl);
    } else {
        wcv_kernel<<<1728, 256, 0, stream>>>(w_conv, wth, wtl);
    }
    if (srt){
        hipMemsetAsync(hist, 0, SNBINS*sizeof(int), stream);
        shist_kernel<<<MTOT/256, 256, 0, stream>>>(p, hist);
        sscan1_kernel<<<SNB_BLOCKS, 256, 0, stream>>>(hist, offs, bsum);
        sscan2_kernel<<<1, 256, 0, stream>>>(bsum);
        sscan3_kernel<<<SNB_BLOCKS, 256, 0, stream>>>(offs, bsum);
        sscatter_kernel<<<MTOT/256, 256, 0, stream>>>(p, offs, sortpos, origid, ps);
    }

    for (int i = 0; i < 8; i++){
        int D = DS[i]; double gd = GS[i];
        int ncell = D * D * D;
        int NC2 = 2 * ncell;
        hipMemsetAsync(vgrid, 0xFF, (size_t)NC2*sizeof(int), stream);
        if (ncell <= 2744)
            scatter_kernel<1><<<MTOT/256, 256, ncell*sizeof(int), stream>>>(p, pmin, spp, vgrid, gcs, gd, D);
        else
            scatter_kernel<0><<<MTOT/256, 256, 0, stream>>>(p, pmin, spp, vgrid, gcs, gd, D);
        if (srt)
            vgtrans_kernel<<<(NC2 + 255)/256, 256, 0, stream>>>(vgrid, sortpos, NC2);

        const bool voxel = big && (NC2 < MTOT);

        if (voxel){
            int NC2pad = (NC2 + 31) & ~31;
            nbrv_kernel<<<(NC2pad + 255)/256, 256, 0, stream>>>(vgrid, nbrv, D, NC2, NC2pad);
            mlp_scale_kernel<<<(MTOT*32)/256, 256, 0, stream>>>(
                pp, w1, b1, w_mlp + i*1024, b_mlp + i*32, h0h, h0l);
            vconv_kernel<<<NC2pad/32, 256, 0, stream>>>(
                h0h, h0l, wth + (size_t)(2*i)*27648, wtl + (size_t)(2*i)*27648,
                b_conv + (2*i)*32, nbrv, NC2pad, vv);
            combine_kernel<0><<<MTOT/128, 256, 0, stream>>>(
                h0h, h0l, wth + (size_t)(2*i)*27648, wtl + (size_t)(2*i)*27648,
                vv, gcs, D, nullptr, nullptr, h1h, h1l);
            vconv_kernel<<<NC2pad/32, 256, 0, stream>>>(
                h1h, h1l, wth + (size_t)(2*i+1)*27648, wtl + (size_t)(2*i+1)*27648,
                b_conv + (2*i+1)*32, nbrv, NC2pad, vv);
            combine_kernel<1><<<MTOT/128, 256, 0, stream>>>(
                h1h, h1l, wth + (size_t)(2*i+1)*27648, wtl + (size_t)(2*i+1)*27648,
                vv, gcs, D, h0h, h0l,
                vpl + (size_t)i*8388608, vpl + (size_t)i*8388608 + 4194304);
        } else {
            nbr_kernel<<<MTOT/256, 256, 0, stream>>>(gcs, vgrid, nbr, D);
            mlp_scale_kernel<<<(MTOT*32)/256, 256, 0, stream>>>(
                pp, w1, b1, w_mlp + i*1024, b_mlp + i*32, h0h, h0l);
            if (big){
                conv4_kernel<0><<<MTOT/32, 256, 0, stream>>>(
                    h0h, h0l, wth + (size_t)(2*i)*27648, wtl + (size_t)(2*i)*27648,
                    b_conv + (2*i)*32, nbr, nullptr, nullptr, h1h, h1l);
                conv4_kernel<1><<<MTOT/32, 256, 0, stream>>>(
                    h1h, h1l, wth + (size_t)(2*i+1)*27648, wtl + (size_t)(2*i+1)*27648,
                    b_conv + (2*i+1)*32, nbr, h0h, h0l,
                    vpl + (size_t)i*8388608, vpl + (size_t)i*8388608 + 4194304);
            } else {
                conv_mfma_kernel<0><<<MTOT/64, 256, 0, stream>>>(
                    h0h, h0l, wth + (size_t)(2*i)*27648, wtl + (size_t)(2*i)*27648,
                    b_conv + (2*i)*32, nbr, nullptr, nullptr, nullptr, nullptr,
                    h1h, h1l, nullptr);
                if (i == 0)
                    conv_mfma_kernel<2><<<MTOT/64, 256, 0, stream>>>(
                        h1h, h1l, wth + (size_t)(2*i+1)*27648, wtl + (size_t)(2*i+1)*27648,
                        b_conv + (2*i+1)*32, nbr, h0h, h0l, w2 + i*32*128, b2,
                        nullptr, nullptr, out);
                else
                    conv_mfma_kernel<1><<<MTOT/64, 256, 0, stream>>>(
                        h1h, h1l, wth + (size_t)(2*i+1)*27648, wtl + (size_t)(2*i+1)*27648,
                        b_conv + (2*i+1)*32, nbr, h0h, h0l, w2 + i*32*128, nullptr,
                        nullptr, nullptr, out);
            }
        }
    }
    if (big)
        mlp2_kernel<<<MTOT/64, 256, 0, stream>>>(vpl, w2th, w2tl, b2, oid, out);
}

// Round 18
// 844.434 us; speedup vs baseline: 1.0665x; 1.0665x over previous
//
#include <hip/hip_runtime.h>

#define MTOT 131072   // b*n
#define NB   65536    // n per batch

typedef __attribute__((ext_vector_type(8))) __bf16 bf16x8;
typedef __attribute__((ext_vector_type(4))) __bf16 bf16x4;
typedef __attribute__((ext_vector_type(4))) float  f32x4;

// ---------------------------------------------------------------- pmin
__global__ void pmin_init_kernel(float* pmin){
    if (threadIdx.x < 6) pmin[threadIdx.x] = 2.0f;   // p in [0,1)
}

__global__ void pmin_kernel(const float* __restrict__ p, float* __restrict__ pmin){
    int bi = blockIdx.y;
    float m0 = 2.f, m1 = 2.f, m2 = 2.f;
    for (int ni = blockIdx.x * blockDim.x + threadIdx.x; ni < NB; ni += gridDim.x * blockDim.x){
        const float* pp = p + ((size_t)bi * NB + ni) * 3;
        m0 = fminf(m0, pp[0]); m1 = fminf(m1, pp[1]); m2 = fminf(m2, pp[2]);
    }
    #pragma unroll
    for (int o = 32; o > 0; o >>= 1){
        m0 = fminf(m0, __shfl_down(m0, o, 64));
        m1 = fminf(m1, __shfl_down(m1, o, 64));
        m2 = fminf(m2, __shfl_down(m2, o, 64));
    }
    if ((threadIdx.x & 63) == 0){
        atomicMin((int*)(pmin + bi*3 + 0), __float_as_int(m0));
        atomicMin((int*)(pmin + bi*3 + 1), __float_as_int(m1));
        atomicMin((int*)(pmin + bi*3 + 2), __float_as_int(m2));
    }
}

// ---------------------------------------------------------------- voxel scatter (atomicMax of ids)
// f64 voxelization (floor(p/g) in double) matches the numpy f64 reference bit-exactly.
template<int USE_LDS>
__global__ void scatter_kernel(const float* __restrict__ p, const float* __restrict__ pmin,
                               int* __restrict__ vgrid, int* __restrict__ gcbuf,
                               double gd, int D){
    extern __shared__ int lgrid[];
    int m  = blockIdx.x * blockDim.x + threadIdx.x;
    int bi = m >> 16;
    double px = (double)p[m*3], py = (double)p[m*3+1], pz = (double)p[m*3+2];
    int gx = (int)floor(px / gd) - (int)floor((double)pmin[bi*3+0] / gd);
    int gy = (int)floor(py / gd) - (int)floor((double)pmin[bi*3+1] / gd);
    int gz = (int)floor(pz / gd) - (int)floor((double)pmin[bi*3+2] / gd);
    gcbuf[m] = (gx << 20) | (gy << 10) | gz;
    int cell = (gx * D + gy) * D + gz;

    if (!USE_LDS){
        atomicMax(vgrid + bi * D * D * D + cell, m);
        return;
    }
    int ncell = D * D * D;
    for (int c = threadIdx.x; c < ncell; c += 256) lgrid[c] = -1;
    __syncthreads();
    atomicMax(&lgrid[cell], m);
    __syncthreads();
    int* vg = vgrid + bi * ncell;
    for (int c = threadIdx.x; c < ncell; c += 256){
        int v = lgrid[c];
        if (v >= 0) atomicMax(vg + c, v);
    }
}

// ---------------------------------------------------------------- 27-tap neighbor table (per point; scales 0-1)
__global__ void nbr_kernel(const int* __restrict__ gcbuf, const int* __restrict__ vgrid,
                           int* __restrict__ nbr, int D){
    int m  = blockIdx.x * blockDim.x + threadIdx.x;
    int bi = m >> 16;
    int pk = gcbuf[m];
    int gx = pk >> 20, gy = (pk >> 10) & 1023, gz = pk & 1023;
    #pragma unroll
    for (int k = 0; k < 27; k++){
        int v;
        if (k == 13){
            v = m;
        } else {
            int x = gx + (k/9) - 1;
            int y = gy + ((k/3)%3) - 1;
            int z = gz + (k%3) - 1;
            if (x < 0 || y < 0 || z < 0 || x >= D || y >= D || z >= D) v = -1;
            else v = vgrid[((bi * D + x) * D + y) * D + z];
        }
        nbr[k * MTOT + m] = v;
    }
}

// ---------------------------------------------------------------- 27-tap neighbor table (per CELL; voxel scales)
__global__ void nbrv_kernel(const int* __restrict__ vgrid, int* __restrict__ nbrv,
                            int D, int NC2, int NC2pad){
    int ci = blockIdx.x * 256 + threadIdx.x;
    if (ci >= NC2pad) return;
    int D3 = D * D * D;
    int bi = (ci >= D3) ? 1 : 0;
    int r  = ci - bi * D3;
    int x = r / (D*D), y = (r / D) % D, z = r % D;
    #pragma unroll
    for (int k = 0; k < 27; k++){
        int v = -1;
        if (ci < NC2){
            int nx = x + (k/9) - 1;
            int ny = y + ((k/3)%3) - 1;
            int nz = z + (k%3) - 1;
            if (nx >= 0 && ny >= 0 && nz >= 0 && nx < D && ny < D && nz < D)
                v = vgrid[bi * D3 + ((nx * D + ny) * D + nz)];
        }
        nbrv[k * NC2pad + ci] = v;
    }
}

// ---------------------------------------------------------------- W_conv -> WAVE-LINEAR bf16 hi/lo planes (big path)
// wt2[cv][k][half][l][e] = W[cv][k][ j=(l>>4)*8+e ][ c=half*16+(l&15) ]
__global__ void wcv_wave_kernel(const float* __restrict__ w_conv,
                                __bf16* __restrict__ wth, __bf16* __restrict__ wtl){
    int o = blockIdx.x * 256 + threadIdx.x;          // 442368 total
    int cv = o / 27648, r = o % 27648;
    int k = r / 1024, q = r % 1024;
    int half = q >> 9, t = q & 511;
    int l = t >> 3, e = t & 7;
    int c = half*16 + (l & 15);
    int j = (l >> 4)*8 + e;
    float x = w_conv[cv*27648 + k*1024 + j*32 + c];
    __bf16 hi = (__bf16)x;
    wth[o] = hi;
    wtl[o] = (__bf16)(x - (float)hi);
}

// ---------------------------------------------------------------- W_conv -> [k][c][j] layout (fallback path)
__global__ void wcv_kernel(const float* __restrict__ w_conv,
                           __bf16* __restrict__ wth, __bf16* __restrict__ wtl){
    int o = blockIdx.x * 256 + threadIdx.x;          // 442368 total
    int cv = o / 27648, r = o % 27648;
    int k = r / 1024, q = r % 1024, c = q / 32, j = q % 32;
    float x = w_conv[cv*27648 + k*1024 + j*32 + c];
    __bf16 hi = (__bf16)x;
    wth[o] = hi;
    wtl[o] = (__bf16)(x - (float)hi);
}

// ---------------------------------------------------------------- w2 -> [kc][c(128)][j(32)] bf16 hi/lo
__global__ void w2t_kernel(const float* __restrict__ w2,
                           __bf16* __restrict__ w2th, __bf16* __restrict__ w2tl){
    int o = blockIdx.x * 256 + threadIdx.x;          // 32768 total
    int kc = o >> 12, r = o & 4095, c = r >> 5, j = r & 31;
    float x = w2[(kc*32 + j)*128 + c];
    __bf16 hi = (__bf16)x;
    w2th[o] = hi;
    w2tl[o] = (__bf16)(x - (float)hi);
}

// ---------------------------------------------------------------- fused mlp1 + per-scale mlp -> bf16 hi/lo planes
__global__ void mlp_scale_kernel(const float* __restrict__ p, const float* __restrict__ w1,
                                 const float* __restrict__ b1,
                                 const float* __restrict__ w, const float* __restrict__ b,
                                 __bf16* __restrict__ h0h, __bf16* __restrict__ h0l){
    int t = blockIdx.x * blockDim.x + threadIdx.x;
    int c = t & 31, m = t >> 5;
    float x = p[m*3+0], y = p[m*3+1], z = p[m*3+2];
    float acc = b[c];
    #pragma unroll
    for (int j = 0; j < 32; j++){
        float ptsj = b1[j] + x * w1[j] + y * w1[32 + j] + z * w1[64 + j];
        acc += ptsj * w[j*32 + c];
    }
    __bf16 hi = (__bf16)acc;
    h0h[t] = hi;
    h0l[t] = (__bf16)(acc - (float)hi);
}

// ================================================================ BIG-WS PATH
// conv4 (scales 0-1): 4-way tap split + 2-stage pipeline + wave-linear W
// + wave-uniform empty-tap MFMA skip (scale 0: ~36% of half-wave tap groups
// are fully masked; skipped group contributes exactly acc+0*B = acc, bitwise-same).
// MODE 0: h1 planes = conv(f) + f
// MODE 1: v planes  = conv(f) + f + h0
template<int MODE>
__global__ __launch_bounds__(256)
void conv4_kernel(const __bf16* __restrict__ fh, const __bf16* __restrict__ fl,
                  const __bf16* __restrict__ wth, const __bf16* __restrict__ wtl,
                  const float* __restrict__ bias, const int* __restrict__ nbr,
                  const __bf16* __restrict__ r2h, const __bf16* __restrict__ r2l,
                  __bf16* __restrict__ outh, __bf16* __restrict__ outl)
{
    __shared__ float buf0[32][33], buf1[32][33];
    int tid  = threadIdx.x;
    int lane = tid & 63, w = tid >> 6;
    int col  = lane & 15, kq = lane >> 4;
    int ptA  = blockIdx.x * 32 + col, ptB = ptA + 16;
    const int fragoff = kq * 8;

    f32x4 acc00, acc01, acc10, acc11;
    if (w == 0){
        float bv0 = bias[col], bv1 = bias[col + 16];
        acc00 = (f32x4){bv0,bv0,bv0,bv0}; acc01 = (f32x4){bv1,bv1,bv1,bv1};
        acc10 = (f32x4){bv0,bv0,bv0,bv0}; acc11 = (f32x4){bv1,bv1,bv1,bv1};
    } else {
        acc00 = (f32x4){0,0,0,0}; acc01 = (f32x4){0,0,0,0};
        acc10 = (f32x4){0,0,0,0}; acc11 = (f32x4){0,0,0,0};
    }

    int k0 = w * 7, k1 = (k0 + 7 < 27) ? k0 + 7 : 27;

    int idc = nbr[k0 * MTOT + ptA];
    int jdc = nbr[k0 * MTOT + ptB];
    int idn = (k0 + 1 < k1) ? nbr[(k0+1) * MTOT + ptA] : 0;
    int jdn = (k0 + 1 < k1) ? nbr[(k0+1) * MTOT + ptB] : 0;
    size_t oc0 = (size_t)(idc < 0 ? 0 : idc) * 32 + fragoff;
    size_t oc1 = (size_t)(jdc < 0 ? 0 : jdc) * 32 + fragoff;
    bf16x8 a0h = *(const bf16x8*)(fh + oc0);
    bf16x8 a0l = *(const bf16x8*)(fl + oc0);
    bf16x8 a1h = *(const bf16x8*)(fh + oc1);
    bf16x8 a1l = *(const bf16x8*)(fl + oc1);
    bool mc0 = idc < 0, mc1 = jdc < 0;

    #pragma unroll 1
    for (int k = k0; k < k1; k++){
        int idn2 = 0, jdn2 = 0;
        if (k + 2 < k1){ idn2 = nbr[(k+2) * MTOT + ptA]; jdn2 = nbr[(k+2) * MTOT + ptB]; }
        size_t on0 = (size_t)(idn < 0 ? 0 : idn) * 32 + fragoff;
        size_t on1 = (size_t)(jdn < 0 ? 0 : jdn) * 32 + fragoff;
        bf16x8 na0h = *(const bf16x8*)(fh + on0);
        bf16x8 na0l = *(const bf16x8*)(fl + on0);
        bf16x8 na1h = *(const bf16x8*)(fh + on1);
        bf16x8 na1l = *(const bf16x8*)(fl + on1);
        bool nm0 = idn < 0, nm1 = jdn < 0;

        const __bf16* wb = wth + (size_t)k*1024 + lane*8;
        const __bf16* wc = wtl + (size_t)k*1024 + lane*8;
        bf16x8 b0h = *(const bf16x8*)(wb);
        bf16x8 b1h = *(const bf16x8*)(wb + 512);
        bf16x8 b0l = *(const bf16x8*)(wc);
        bf16x8 b1l = *(const bf16x8*)(wc + 512);

        bf16x8 z = {};
        // wave-uniform skip: if a 16-point half-group has NO live tap, its 6 MFMAs
        // would all compute acc += 0*B -> skip them (bitwise-identical result).
        if (__any(!mc0)){
            bf16x8 xa0h = mc0 ? z : a0h, xa0l = mc0 ? z : a0l;
            acc00 = __builtin_amdgcn_mfma_f32_16x16x32_bf16(xa0h, b0h, acc00, 0,0,0);
            acc00 = __builtin_amdgcn_mfma_f32_16x16x32_bf16(xa0h, b0l, acc00, 0,0,0);
            acc00 = __builtin_amdgcn_mfma_f32_16x16x32_bf16(xa0l, b0h, acc00, 0,0,0);
            acc01 = __builtin_amdgcn_mfma_f32_16x16x32_bf16(xa0h, b1h, acc01, 0,0,0);
            acc01 = __builtin_amdgcn_mfma_f32_16x16x32_bf16(xa0h, b1l, acc01, 0,0,0);
            acc01 = __builtin_amdgcn_mfma_f32_16x16x32_bf16(xa0l, b1h, acc01, 0,0,0);
        }
        if (__any(!mc1)){
            bf16x8 xa1h = mc1 ? z : a1h, xa1l = mc1 ? z : a1l;
            acc10 = __builtin_amdgcn_mfma_f32_16x16x32_bf16(xa1h, b0h, acc10, 0,0,0);
            acc10 = __builtin_amdgcn_mfma_f32_16x16x32_bf16(xa1h, b0l, acc10, 0,0,0);
            acc10 = __builtin_amdgcn_mfma_f32_16x16x32_bf16(xa1l, b0h, acc10, 0,0,0);
            acc11 = __builtin_amdgcn_mfma_f32_16x16x32_bf16(xa1h, b1h, acc11, 0,0,0);
            acc11 = __builtin_amdgcn_mfma_f32_16x16x32_bf16(xa1h, b1l, acc11, 0,0,0);
            acc11 = __builtin_amdgcn_mfma_f32_16x16x32_bf16(xa1l, b1h, acc11, 0,0,0);
        }

        a0h = na0h; a0l = na0l; a1h = na1h; a1l = na1l;
        mc0 = nm0; mc1 = nm1; idn = idn2; jdn = jdn2;
    }

    // tree combine: final = (bias+T0+T2) + (T1+T3)
    if (w == 2){
        #pragma unroll
        for (int r = 0; r < 4; r++){
            buf0[kq*4 + r][col]           = acc00[r];
            buf0[kq*4 + r][col + 16]      = acc01[r];
            buf0[16 + kq*4 + r][col]      = acc10[r];
            buf0[16 + kq*4 + r][col + 16] = acc11[r];
        }
    } else if (w == 3){
        #pragma unroll
        for (int r = 0; r < 4; r++){
            buf1[kq*4 + r][col]           = acc00[r];
            buf1[kq*4 + r][col + 16]      = acc01[r];
            buf1[16 + kq*4 + r][col]      = acc10[r];
            buf1[16 + kq*4 + r][col + 16] = acc11[r];
        }
    }
    __syncthreads();
    if (w == 0){
        #pragma unroll
        for (int r = 0; r < 4; r++){
            acc00[r] += buf0[kq*4 + r][col];
            acc01[r] += buf0[kq*4 + r][col + 16];
            acc10[r] += buf0[16 + kq*4 + r][col];
            acc11[r] += buf0[16 + kq*4 + r][col + 16];
        }
    } else if (w == 1){
        #pragma unroll
        for (int r = 0; r < 4; r++){
            acc00[r] += buf1[kq*4 + r][col];
            acc01[r] += buf1[kq*4 + r][col + 16];
            acc10[r] += buf1[16 + kq*4 + r][col];
            acc11[r] += buf1[16 + kq*4 + r][col + 16];
        }
    }
    __syncthreads();
    if (w == 1){
        #pragma unroll
        for (int r = 0; r < 4; r++){
            buf1[kq*4 + r][col]           = acc00[r];
            buf1[kq*4 + r][col + 16]      = acc01[r];
            buf1[16 + kq*4 + r][col]      = acc10[r];
            buf1[16 + kq*4 + r][col + 16] = acc11[r];
        }
    }
    __syncthreads();
    if (w == 0){
        #pragma unroll
        for (int r = 0; r < 4; r++){
            buf0[kq*4 + r][col]           = acc00[r] + buf1[kq*4 + r][col];
            buf0[kq*4 + r][col + 16]      = acc01[r] + buf1[kq*4 + r][col + 16];
            buf0[16 + kq*4 + r][col]      = acc10[r] + buf1[16 + kq*4 + r][col];
            buf0[16 + kq*4 + r][col + 16] = acc11[r] + buf1[16 + kq*4 + r][col + 16];
        }
    }
    __syncthreads();

    int pt = tid >> 3, c0 = (tid & 7) * 4;
    size_t g = (size_t)(blockIdx.x * 32 + pt) * 32 + c0;
    bf16x4 rh = *(const bf16x4*)(fh + g);
    bf16x4 rl = *(const bf16x4*)(fl + g);
    bf16x4 oh4, ol4;
    if (MODE == 0){
        #pragma unroll
        for (int j = 0; j < 4; j++){
            float v = buf0[pt][c0 + j] + (float)rh[j] + (float)rl[j];
            __bf16 hi = (__bf16)v;
            oh4[j] = hi;
            ol4[j] = (__bf16)(v - (float)hi);
        }
    } else {
        bf16x4 sh = *(const bf16x4*)(r2h + g);
        bf16x4 sl = *(const bf16x4*)(r2l + g);
        #pragma unroll
        for (int j = 0; j < 4; j++){
            float v = buf0[pt][c0 + j] + (float)rh[j] + (float)rl[j]
                                       + (float)sh[j] + (float)sl[j];
            __bf16 hi = (__bf16)v;
            oh4[j] = hi;
            ol4[j] = (__bf16)(v - (float)hi);
        }
    }
    *(bf16x4*)(outh + g) = oh4;
    *(bf16x4*)(outl + g) = ol4;
}

// vconv: conv4 over CELLS, 26 taps (k=13 center handled per-point in combine).
__global__ __launch_bounds__(256)
void vconv_kernel(const __bf16* __restrict__ fh, const __bf16* __restrict__ fl,
                  const __bf16* __restrict__ wth, const __bf16* __restrict__ wtl,
                  const float* __restrict__ bias, const int* __restrict__ nbrv,
                  int NC2pad, float* __restrict__ vv)
{
    __shared__ float buf0[32][33], buf1[32][33];
    int tid  = threadIdx.x;
    int lane = tid & 63, w = tid >> 6;
    int col  = lane & 15, kq = lane >> 4;
    int ptA  = blockIdx.x * 32 + col, ptB = ptA + 16;
    const int fragoff = kq * 8;

    f32x4 acc00, acc01, acc10, acc11;
    if (w == 0){
        float bv0 = bias[col], bv1 = bias[col + 16];
        acc00 = (f32x4){bv0,bv0,bv0,bv0}; acc01 = (f32x4){bv1,bv1,bv1,bv1};
        acc10 = (f32x4){bv0,bv0,bv0,bv0}; acc11 = (f32x4){bv1,bv1,bv1,bv1};
    } else {
        acc00 = (f32x4){0,0,0,0}; acc01 = (f32x4){0,0,0,0};
        acc10 = (f32x4){0,0,0,0}; acc11 = (f32x4){0,0,0,0};
    }

    int k0 = (w == 0) ? 0 : (w == 1) ? 7 : (w == 2) ? 14 : 21;
    int k1 = (w == 0) ? 7 : (w == 1) ? 13 : (w == 2) ? 21 : 27;

    int idc = nbrv[k0 * NC2pad + ptA];
    int jdc = nbrv[k0 * NC2pad + ptB];
    int idn = (k0 + 1 < k1) ? nbrv[(k0+1) * NC2pad + ptA] : 0;
    int jdn = (k0 + 1 < k1) ? nbrv[(k0+1) * NC2pad + ptB] : 0;
    size_t oc0 = (size_t)(idc < 0 ? 0 : idc) * 32 + fragoff;
    size_t oc1 = (size_t)(jdc < 0 ? 0 : jdc) * 32 + fragoff;
    bf16x8 a0h = *(const bf16x8*)(fh + oc0);
    bf16x8 a0l = *(const bf16x8*)(fl + oc0);
    bf16x8 a1h = *(const bf16x8*)(fh + oc1);
    bf16x8 a1l = *(const bf16x8*)(fl + oc1);
    bool mc0 = idc < 0, mc1 = jdc < 0;

    #pragma unroll 1
    for (int k = k0; k < k1; k++){
        int idn2 = 0, jdn2 = 0;
        if (k + 2 < k1){ idn2 = nbrv[(k+2) * NC2pad + ptA]; jdn2 = nbrv[(k+2) * NC2pad + ptB]; }
        size_t on0 = (size_t)(idn < 0 ? 0 : idn) * 32 + fragoff;
        size_t on1 = (size_t)(jdn < 0 ? 0 : jdn) * 32 + fragoff;
        bf16x8 na0h = *(const bf16x8*)(fh + on0);
        bf16x8 na0l = *(const bf16x8*)(fl + on0);
        bf16x8 na1h = *(const bf16x8*)(fh + on1);
        bf16x8 na1l = *(const bf16x8*)(fl + on1);
        bool nm0 = idn < 0, nm1 = jdn < 0;

        const __bf16* wb = wth + (size_t)k*1024 + lane*8;
        const __bf16* wc = wtl + (size_t)k*1024 + lane*8;
        bf16x8 b0h = *(const bf16x8*)(wb);
        bf16x8 b1h = *(const bf16x8*)(wb + 512);
        bf16x8 b0l = *(const bf16x8*)(wc);
        bf16x8 b1l = *(const bf16x8*)(wc + 512);

        bf16x8 z = {};
        bf16x8 xa0h = mc0 ? z : a0h, xa0l = mc0 ? z : a0l;
        bf16x8 xa1h = mc1 ? z : a1h, xa1l = mc1 ? z : a1l;

        acc00 = __builtin_amdgcn_mfma_f32_16x16x32_bf16(xa0h, b0h, acc00, 0,0,0);
        acc00 = __builtin_amdgcn_mfma_f32_16x16x32_bf16(xa0h, b0l, acc00, 0,0,0);
        acc00 = __builtin_amdgcn_mfma_f32_16x16x32_bf16(xa0l, b0h, acc00, 0,0,0);
        acc01 = __builtin_amdgcn_mfma_f32_16x16x32_bf16(xa0h, b1h, acc01, 0,0,0);
        acc01 = __builtin_amdgcn_mfma_f32_16x16x32_bf16(xa0h, b1l, acc01, 0,0,0);
        acc01 = __builtin_amdgcn_mfma_f32_16x16x32_bf16(xa0l, b1h, acc01, 0,0,0);
        acc10 = __builtin_amdgcn_mfma_f32_16x16x32_bf16(xa1h, b0h, acc10, 0,0,0);
        acc10 = __builtin_amdgcn_mfma_f32_16x16x32_bf16(xa1h, b0l, acc10, 0,0,0);
        acc10 = __builtin_amdgcn_mfma_f32_16x16x32_bf16(xa1l, b0h, acc10, 0,0,0);
        acc11 = __builtin_amdgcn_mfma_f32_16x16x32_bf16(xa1h, b1h, acc11, 0,0,0);
        acc11 = __builtin_amdgcn_mfma_f32_16x16x32_bf16(xa1h, b1l, acc11, 0,0,0);
        acc11 = __builtin_amdgcn_mfma_f32_16x16x32_bf16(xa1l, b1h, acc11, 0,0,0);

        a0h = na0h; a0l = na0l; a1h = na1h; a1l = na1l;
        mc0 = nm0; mc1 = nm1; idn = idn2; jdn = jdn2;
    }

    if (w == 2){
        #pragma unroll
        for (int r = 0; r < 4; r++){
            buf0[kq*4 + r][col]           = acc00[r];
            buf0[kq*4 + r][col + 16]      = acc01[r];
            buf0[16 + kq*4 + r][col]      = acc10[r];
            buf0[16 + kq*4 + r][col + 16] = acc11[r];
        }
    } else if (w == 3){
        #pragma unroll
        for (int r = 0; r < 4; r++){
            buf1[kq*4 + r][col]           = acc00[r];
            buf1[kq*4 + r][col + 16]      = acc01[r];
            buf1[16 + kq*4 + r][col]      = acc10[r];
            buf1[16 + kq*4 + r][col + 16] = acc11[r];
        }
    }
    __syncthreads();
    if (w == 0){
        #pragma unroll
        for (int r = 0; r < 4; r++){
            acc00[r] += buf0[kq*4 + r][col];
            acc01[r] += buf0[kq*4 + r][col + 16];
            acc10[r] += buf0[16 + kq*4 + r][col];
            acc11[r] += buf0[16 + kq*4 + r][col + 16];
        }
    } else if (w == 1){
        #pragma unroll
        for (int r = 0; r < 4; r++){
            acc00[r] += buf1[kq*4 + r][col];
            acc01[r] += buf1[kq*4 + r][col + 16];
            acc10[r] += buf1[16 + kq*4 + r][col];
            acc11[r] += buf1[16 + kq*4 + r][col + 16];
        }
    }
    __syncthreads();
    if (w == 1){
        #pragma unroll
        for (int r = 0; r < 4; r++){
            buf1[kq*4 + r][col]           = acc00[r];
            buf1[kq*4 + r][col + 16]      = acc01[r];
            buf1[16 + kq*4 + r][col]      = acc10[r];
            buf1[16 + kq*4 + r][col + 16] = acc11[r];
        }
    }
    __syncthreads();
    if (w == 0){
        #pragma unroll
        for (int r = 0; r < 4; r++){
            buf0[kq*4 + r][col]           = acc00[r] + buf1[kq*4 + r][col];
            buf0[kq*4 + r][col + 16]      = acc01[r] + buf1[kq*4 + r][col + 16];
            buf0[16 + kq*4 + r][col]      = acc10[r] + buf1[16 + kq*4 + r][col];
            buf0[16 + kq*4 + r][col + 16] = acc11[r] + buf1[16 + kq*4 + r][col + 16];
        }
    }
    __syncthreads();

    int pt = tid >> 3, c0 = (tid & 7) * 4;
    float* o = vv + (size_t)(blockIdx.x * 32 + pt) * 32 + c0;
    ((float4*)o)[0] = make_float4(buf0[pt][c0], buf0[pt][c0+1], buf0[pt][c0+2], buf0[pt][c0+3]);
}

// combine: per-point center term + voxel-conv gather + residual(s).
template<int MODE>
__global__ __launch_bounds__(256)
void combine_kernel(const __bf16* __restrict__ fh, const __bf16* __restrict__ fl,
                    const __bf16* __restrict__ wth, const __bf16* __restrict__ wtl,
                    const float* __restrict__ vv, const int* __restrict__ gcbuf, int D,
                    const __bf16* __restrict__ r2h, const __bf16* __restrict__ r2l,
                    __bf16* __restrict__ outh, __bf16* __restrict__ outl)
{
    __shared__ float vsh[128][33];
    int tid  = threadIdx.x;
    int lane = tid & 63, w = tid >> 6;
    int col  = lane & 15, kq = lane >> 4;
    const int fragoff = kq * 8;
    int mB  = blockIdx.x * 128 + w * 32;
    int ptA = mB + col, ptB = ptA + 16;

    size_t oA = (size_t)ptA * 32 + fragoff;
    size_t oB = (size_t)ptB * 32 + fragoff;
    bf16x8 a0h = *(const bf16x8*)(fh + oA);
    bf16x8 a0l = *(const bf16x8*)(fl + oA);
    bf16x8 a1h = *(const bf16x8*)(fh + oB);
    bf16x8 a1l = *(const bf16x8*)(fl + oB);

    const __bf16* wb = wth + 13*1024 + lane*8;
    const __bf16* wc = wtl + 13*1024 + lane*8;
    bf16x8 b0h = *(const bf16x8*)(wb);
    bf16x8 b1h = *(const bf16x8*)(wb + 512);
    bf16x8 b0l = *(const bf16x8*)(wc);
    bf16x8 b1l = *(const bf16x8*)(wc + 512);

    f32x4 acc00 = {0,0,0,0}, acc01 = {0,0,0,0}, acc10 = {0,0,0,0}, acc11 = {0,0,0,0};
    acc00 = __builtin_amdgcn_mfma_f32_16x16x32_bf16(a0h, b0h, acc00, 0,0,0);
    acc00 = __builtin_amdgcn_mfma_f32_16x16x32_bf16(a0h, b0l, acc00, 0,0,0);
    acc00 = __builtin_amdgcn_mfma_f32_16x16x32_bf16(a0l, b0h, acc00, 0,0,0);
    acc01 = __builtin_amdgcn_mfma_f32_16x16x32_bf16(a0h, b1h, acc01, 0,0,0);
    acc01 = __builtin_amdgcn_mfma_f32_16x16x32_bf16(a0h, b1l, acc01, 0,0,0);
    acc01 = __builtin_amdgcn_mfma_f32_16x16x32_bf16(a0l, b1h, acc01, 0,0,0);
    acc10 = __builtin_amdgcn_mfma_f32_16x16x32_bf16(a1h, b0h, acc10, 0,0,0);
    acc10 = __builtin_amdgcn_mfma_f32_16x16x32_bf16(a1h, b0l, acc10, 0,0,0);
    acc10 = __builtin_amdgcn_mfma_f32_16x16x32_bf16(a1l, b0h, acc10, 0,0,0);
    acc11 = __builtin_amdgcn_mfma_f32_16x16x32_bf16(a1h, b1h, acc11, 0,0,0);
    acc11 = __builtin_amdgcn_mfma_f32_16x16x32_bf16(a1h, b1l, acc11, 0,0,0);
    acc11 = __builtin_amdgcn_mfma_f32_16x16x32_bf16(a1l, b1h, acc11, 0,0,0);

    #pragma unroll
    for (int r = 0; r < 4; r++){
        vsh[w*32 + kq*4 + r][col]           = acc00[r];
        vsh[w*32 + kq*4 + r][col + 16]      = acc01[r];
        vsh[w*32 + 16 + kq*4 + r][col]      = acc10[r];
        vsh[w*32 + 16 + kq*4 + r][col + 16] = acc11[r];
    }
    __syncthreads();

    int pt = tid >> 1, c0 = (tid & 1) * 16;
    int m  = blockIdx.x * 128 + pt;
    int pk = gcbuf[m];
    int bi = m >> 16;
    int gx = pk >> 20, gy = (pk >> 10) & 1023, gz = pk & 1023;
    int ci = ((bi * D + gx) * D + gy) * D + gz;

    const float* vrow = vv + (size_t)ci * 32 + c0;
    size_t g = (size_t)m * 32 + c0;
    bf16x8 rh0 = *(const bf16x8*)(fh + g);
    bf16x8 rh1 = *(const bf16x8*)(fh + g + 8);
    bf16x8 rl0 = *(const bf16x8*)(fl + g);
    bf16x8 rl1 = *(const bf16x8*)(fl + g + 8);
    bf16x8 sh0, sh1, sl0, sl1;
    if (MODE == 1){
        sh0 = *(const bf16x8*)(r2h + g);
        sh1 = *(const bf16x8*)(r2h + g + 8);
        sl0 = *(const bf16x8*)(r2l + g);
        sl1 = *(const bf16x8*)(r2l + g + 8);
    }
    bf16x8 oh0, oh1, ol0, ol1;
    #pragma unroll
    for (int j = 0; j < 8; j++){
        float v = vsh[pt][c0 + j] + vrow[j] + (float)rh0[j] + (float)rl0[j];
        if (MODE == 1) v += (float)sh0[j] + (float)sl0[j];
        __bf16 hi = (__bf16)v;
        oh0[j] = hi; ol0[j] = (__bf16)(v - (float)hi);
    }
    #pragma unroll
    for (int j = 0; j < 8; j++){
        float v = vsh[pt][c0 + 8 + j] + vrow[8 + j] + (float)rh1[j] + (float)rl1[j];
        if (MODE == 1) v += (float)sh1[j] + (float)sl1[j];
        __bf16 hi = (__bf16)v;
        oh1[j] = hi; ol1[j] = (__bf16)(v - (float)hi);
    }
    *(bf16x8*)(outh + g)     = oh0;
    *(bf16x8*)(outh + g + 8) = oh1;
    *(bf16x8*)(outl + g)     = ol0;
    *(bf16x8*)(outl + g + 8) = ol1;
}

// mlp2: out[m,128] = b2 + sum_kc v_kc[m,32] @ w2[kc] (3-term hi/lo MFMA).
__global__ __launch_bounds__(256)
void mlp2_kernel(const __bf16* __restrict__ vplanes,
                 const __bf16* __restrict__ w2th, const __bf16* __restrict__ w2tl,
                 const float* __restrict__ b2, float* __restrict__ out)
{
    int tid  = threadIdx.x;
    int lane = tid & 63, w = tid >> 6;
    int col  = lane & 15, kq = lane >> 4;
    const int fragoff = kq * 8;
    int pbase = blockIdx.x * 128 + w * 32;
    size_t oA = (size_t)(pbase + col) * 32 + fragoff;
    size_t oB = (size_t)(pbase + 16 + col) * 32 + fragoff;

    f32x4 acc[4][4];
    #pragma unroll
    for (int s = 0; s < 4; s++)
        #pragma unroll
        for (int q = 0; q < 4; q++) acc[s][q] = (f32x4){0,0,0,0};

    bf16x8 a0h = *(const bf16x8*)(vplanes + oA);
    bf16x8 a0l = *(const bf16x8*)(vplanes + 4194304 + oA);
    bf16x8 a1h = *(const bf16x8*)(vplanes + oB);
    bf16x8 a1l = *(const bf16x8*)(vplanes + 4194304 + oB);

    #pragma unroll 1
    for (int kc = 0; kc < 8; kc++){
        bf16x8 na0h, na0l, na1h, na1l;
        if (kc < 7){
            const __bf16* fnh = vplanes + (size_t)(kc+1) * 8388608;
            const __bf16* fnl = fnh + 4194304;
            na0h = *(const bf16x8*)(fnh + oA);
            na0l = *(const bf16x8*)(fnl + oA);
            na1h = *(const bf16x8*)(fnh + oB);
            na1l = *(const bf16x8*)(fnl + oB);
        } else {
            na0h = a0h; na0l = a0l; na1h = a1h; na1l = a1l;
        }

        const __bf16* wbase  = w2th + (size_t)kc * 4096;
        const __bf16* wlbase = w2tl + (size_t)kc * 4096;
        #pragma unroll
        for (int s = 0; s < 4; s++){
            const __bf16* wb = wbase  + (s*32 + col) * 32 + fragoff;
            const __bf16* wc = wlbase + (s*32 + col) * 32 + fragoff;
            bf16x8 b0h = *(const bf16x8*)(wb);
            bf16x8 b1h = *(const bf16x8*)(wb + 512);
            bf16x8 b0l = *(const bf16x8*)(wc);
            bf16x8 b1l = *(const bf16x8*)(wc + 512);

            acc[s][0] = __builtin_amdgcn_mfma_f32_16x16x32_bf16(a0h, b0h, acc[s][0], 0,0,0);
            acc[s][0] = __builtin_amdgcn_mfma_f32_16x16x32_bf16(a0h, b0l, acc[s][0], 0,0,0);
            acc[s][0] = __builtin_amdgcn_mfma_f32_16x16x32_bf16(a0l, b0h, acc[s][0], 0,0,0);
            acc[s][1] = __builtin_amdgcn_mfma_f32_16x16x32_bf16(a0h, b1h, acc[s][1], 0,0,0);
            acc[s][1] = __builtin_amdgcn_mfma_f32_16x16x32_bf16(a0h, b1l, acc[s][1], 0,0,0);
            acc[s][1] = __builtin_amdgcn_mfma_f32_16x16x32_bf16(a0l, b1h, acc[s][1], 0,0,0);
            acc[s][2] = __builtin_amdgcn_mfma_f32_16x16x32_bf16(a1h, b0h, acc[s][2], 0,0,0);
            acc[s][2] = __builtin_amdgcn_mfma_f32_16x16x32_bf16(a1h, b0l, acc[s][2], 0,0,0);
            acc[s][2] = __builtin_amdgcn_mfma_f32_16x16x32_bf16(a1l, b0h, acc[s][2], 0,0,0);
            acc[s][3] = __builtin_amdgcn_mfma_f32_16x16x32_bf16(a1h, b1h, acc[s][3], 0,0,0);
            acc[s][3] = __builtin_amdgcn_mfma_f32_16x16x32_bf16(a1h, b1l, acc[s][3], 0,0,0);
            acc[s][3] = __builtin_amdgcn_mfma_f32_16x16x32_bf16(a1l, b1h, acc[s][3], 0,0,0);
        }

        a0h = na0h; a0l = na0l; a1h = na1h; a1l = na1l;
    }

    #pragma unroll
    for (int s = 0; s < 4; s++){
        float bl = b2[s*32 + col], bh = b2[s*32 + 16 + col];
        #pragma unroll
        for (int r = 0; r < 4; r++){
            size_t rowA = (size_t)(pbase + kq*4 + r) * 128;
            size_t rowB = (size_t)(pbase + 16 + kq*4 + r) * 128;
            out[rowA + s*32 + col]      = acc[s][0][r] + bl;
            out[rowA + s*32 + 16 + col] = acc[s][1][r] + bh;
            out[rowB + s*32 + col]      = acc[s][2][r] + bl;
            out[rowB + s*32 + 16 + col] = acc[s][3][r] + bh;
        }
    }
}

// ================================================================ FALLBACK PATH (round-9, verbatim; old W layout)
template<int MODE>
__global__ __launch_bounds__(256)
void conv_mfma_kernel(const __bf16* __restrict__ fh, const __bf16* __restrict__ fl,
                      const __bf16* __restrict__ wth, const __bf16* __restrict__ wtl,
                      const float* __restrict__ bias, const int* __restrict__ nbr,
                      const __bf16* __restrict__ r2h, const __bf16* __restrict__ r2l,
                      const float* __restrict__ w2i, const float* __restrict__ b2,
                      __bf16* __restrict__ outh, __bf16* __restrict__ outl,
                      float* __restrict__ out)
{
    __shared__ float vsh[64][33];
    int tid  = threadIdx.x;
    int lane = tid & 63, wid = tid >> 6;
    int pair = wid >> 1;
    int half = wid & 1;
    int col  = lane & 15, kq = lane >> 4;
    int m0   = blockIdx.x * 64 + pair * 32;
    int ptA  = m0 + col, ptB = ptA + 16;
    const int fragoff = kq * 8;

    f32x4 acc00, acc01, acc10, acc11;
    if (half == 0){
        float bv0 = bias[col], bv1 = bias[col + 16];
        acc00 = (f32x4){bv0,bv0,bv0,bv0}; acc01 = (f32x4){bv1,bv1,bv1,bv1};
        acc10 = (f32x4){bv0,bv0,bv0,bv0}; acc11 = (f32x4){bv1,bv1,bv1,bv1};
    } else {
        acc00 = (f32x4){0,0,0,0}; acc01 = (f32x4){0,0,0,0};
        acc10 = (f32x4){0,0,0,0}; acc11 = (f32x4){0,0,0,0};
    }

    int k0 = half ? 14 : 0;
    int k1 = half ? 27 : 14;
    #pragma unroll 1
    for (int k = k0; k < k1; k++){
        int nb0 = nbr[k * MTOT + ptA];
        int nb1 = nbr[k * MTOT + ptB];
        size_t o0 = (size_t)(nb0 < 0 ? 0 : nb0) * 32 + fragoff;
        size_t o1 = (size_t)(nb1 < 0 ? 0 : nb1) * 32 + fragoff;
        bf16x8 a0h = *(const bf16x8*)(fh + o0);
        bf16x8 a0l = *(const bf16x8*)(fl + o0);
        bf16x8 a1h = *(const bf16x8*)(fh + o1);
        bf16x8 a1l = *(const bf16x8*)(fl + o1);
        bf16x8 z = {};
        if (nb0 < 0){ a0h = z; a0l = z; }
        if (nb1 < 0){ a1h = z; a1l = z; }

        const __bf16* wb = wth + (size_t)k*1024 + col*32 + fragoff;
        const __bf16* wc = wtl + (size_t)k*1024 + col*32 + fragoff;
        bf16x8 b0h = *(const bf16x8*)(wb);
        bf16x8 b1h = *(const bf16x8*)(wb + 512);
        bf16x8 b0l = *(const bf16x8*)(wc);
        bf16x8 b1l = *(const bf16x8*)(wc + 512);

        acc00 = __builtin_amdgcn_mfma_f32_16x16x32_bf16(a0h, b0h, acc00, 0,0,0);
        acc00 = __builtin_amdgcn_mfma_f32_16x16x32_bf16(a0h, b0l, acc00, 0,0,0);
        acc00 = __builtin_amdgcn_mfma_f32_16x16x32_bf16(a0l, b0h, acc00, 0,0,0);
        acc01 = __builtin_amdgcn_mfma_f32_16x16x32_bf16(a0h, b1h, acc01, 0,0,0);
        acc01 = __builtin_amdgcn_mfma_f32_16x16x32_bf16(a0h, b1l, acc01, 0,0,0);
        acc01 = __builtin_amdgcn_mfma_f32_16x16x32_bf16(a0l, b1h, acc01, 0,0,0);
        acc10 = __builtin_amdgcn_mfma_f32_16x16x32_bf16(a1h, b0h, acc10, 0,0,0);
        acc10 = __builtin_amdgcn_mfma_f32_16x16x32_bf16(a1h, b0l, acc10, 0,0,0);
        acc10 = __builtin_amdgcn_mfma_f32_16x16x32_bf16(a1l, b0h, acc10, 0,0,0);
        acc11 = __builtin_amdgcn_mfma_f32_16x16x32_bf16(a1h, b1h, acc11, 0,0,0);
        acc11 = __builtin_amdgcn_mfma_f32_16x16x32_bf16(a1h, b1l, acc11, 0,0,0);
        acc11 = __builtin_amdgcn_mfma_f32_16x16x32_bf16(a1l, b1h, acc11, 0,0,0);
    }

    if (half == 1){
        #pragma unroll
        for (int r = 0; r < 4; r++){
            vsh[pair*32 + kq*4 + r][col]           = acc00[r];
            vsh[pair*32 + kq*4 + r][col + 16]      = acc01[r];
            vsh[pair*32 + 16 + kq*4 + r][col]      = acc10[r];
            vsh[pair*32 + 16 + kq*4 + r][col + 16] = acc11[r];
        }
    }
    __syncthreads();
    if (half == 0){
        #pragma unroll
        for (int r = 0; r < 4; r++){
            vsh[pair*32 + kq*4 + r][col]           += acc00[r];
            vsh[pair*32 + kq*4 + r][col + 16]      += acc01[r];
            vsh[pair*32 + 16 + kq*4 + r][col]      += acc10[r];
            vsh[pair*32 + 16 + kq*4 + r][col + 16] += acc11[r];
        }
    }
    __syncthreads();

    if (MODE == 0){
        int eidx = tid * 8;
        int pt = eidx >> 5, c0 = eidx & 31;
        size_t g = (size_t)blockIdx.x * 2048 + eidx;
        bf16x8 rh = *(const bf16x8*)(fh + g);
        bf16x8 rl = *(const bf16x8*)(fl + g);
        bf16x8 oh8, ol8;
        #pragma unroll
        for (int j = 0; j < 8; j++){
            float v = vsh[pt][c0 + j] + (float)rh[j] + (float)rl[j];
            __bf16 hi = (__bf16)v;
            oh8[j] = hi;
            ol8[j] = (__bf16)(v - (float)hi);
        }
        *(bf16x8*)(outh + g) = oh8;
        *(bf16x8*)(outl + g) = ol8;
    } else {
        int eidx = tid * 8;
        int pt = eidx >> 5, c0 = eidx & 31;
        size_t g = (size_t)blockIdx.x * 2048 + eidx;
        bf16x8 rh = *(const bf16x8*)(fh + g);
        bf16x8 rl = *(const bf16x8*)(fl + g);
        bf16x8 sh = *(const bf16x8*)(r2h + g);
        bf16x8 sl = *(const bf16x8*)(r2l + g);
        #pragma unroll
        for (int j = 0; j < 8; j++)
            vsh[pt][c0 + j] += (float)rh[j] + (float)rl[j] + (float)sh[j] + (float)sl[j];
        __syncthreads();

        int pm = tid & 63;
        int tg = __builtin_amdgcn_readfirstlane(tid >> 6);
        size_t m = (size_t)blockIdx.x * 64 + pm;
        float o32[32];
        float* obase = out + m*128 + tg*32;
        if (MODE == 2){
            #pragma unroll
            for (int o = 0; o < 32; o++) o32[o] = b2[tg*32 + o];
        } else {
            #pragma unroll
            for (int q = 0; q < 8; q++){
                float4 t4 = ((const float4*)obase)[q];
                o32[q*4+0] = t4.x; o32[q*4+1] = t4.y; o32[q*4+2] = t4.z; o32[q*4+3] = t4.w;
            }
        }
        #pragma unroll
        for (int c = 0; c < 32; c++){
            float vc = vsh[pm][c];
            const float* w2r = w2i + c*128 + tg*32;
            #pragma unroll
            for (int o = 0; o < 32; o++) o32[o] += vc * w2r[o];
        }
        #pragma unroll
        for (int q = 0; q < 8; q++)
            ((float4*)obase)[q] = make_float4(o32[q*4+0], o32[q*4+1], o32[q*4+2], o32[q*4+3]);
    }
}

// ---------------------------------------------------------------- launch
extern "C" void kernel_launch(void* const* d_in, const int* in_sizes, int n_in,
                              void* d_out, int out_size, void* d_ws, size_t ws_size,
                              hipStream_t stream)
{
    static const int want[9] = {393216, 96, 32, 8192, 256, 442368, 512, 32768, 128};
    const void* bound[9];
    for (int i = 0; i < 9; i++) bound[i] = d_in[i];
    if (n_in == 9){
        for (int i = 0; i < 9; i++)
            for (int j = 0; j < 9; j++)
                if (in_sizes[j] == want[i]) { bound[i] = d_in[j]; break; }
    }
    const float* p      = (const float*)bound[0];
    const float* w1     = (const float*)bound[1];
    const float* b1     = (const float*)bound[2];
    const float* w_mlp  = (const float*)bound[3];
    const float* b_mlp  = (const float*)bound[4];
    const float* w_conv = (const float*)bound[5];
    const float* b_conv = (const float*)bound[6];
    const float* w2     = (const float*)bound[7];
    const float* b2     = (const float*)bound[8];
    float* out = (float*)d_out;

    char* ws = (char*)d_ws;
    __bf16* h0h  = (__bf16*)(ws);
    __bf16* h0l  = (__bf16*)(ws + 8388608);
    __bf16* h1h  = (__bf16*)(ws + 16777216);
    int*    vgrid= (int*)   (ws + 16777216);            // alias of h1h (dead before h1h written)
    __bf16* h1l  = (__bf16*)(ws + 25165824);
    int*    nbr  = (int*)   (ws + 33554432);            // 14,155,776 B (per-point nbr OR nbrv+vv)
    int*    nbrv = (int*)   (ws + 33554432);
    float*  vv   = (float*) (ws + 33554432 + 6291456);
    __bf16* wth  = (__bf16*)(ws + 47710208);            // 884,736 B
    __bf16* wtl  = (__bf16*)(ws + 48594944);            // 884,736 B
    __bf16* w2th = (__bf16*)(ws + 49479680);            // 65,536 B
    __bf16* w2tl = (__bf16*)(ws + 49545216);            // 65,536 B
    float*  pmin = (float*) (ws + 49610752);            // 256 B
    int*    gcbuf= (int*)   (ws + 49612800);            // 524,288 B
    __bf16* vpl  = (__bf16*)(ws + 50331648);            // 8 x 16 MiB v planes

    const bool big = (ws_size >= 184549376ULL);

    static const double GS[8] = {0.01, 0.02, 0.04, 0.08, 0.16, 0.32, 0.64, 1.28};
    static const int    DS[8] = {101, 51, 26, 14, 8, 5, 3, 2};   // ceil(1/g)+1

    pmin_init_kernel<<<1, 64, 0, stream>>>(pmin);
    pmin_kernel<<<dim3(64, 2), 256, 0, stream>>>(p, pmin);
    if (big){
        wcv_wave_kernel<<<1728, 256, 0, stream>>>(w_conv, wth, wtl);
        w2t_kernel<<<128, 256, 0, stream>>>(w2, w2th, w2tl);
    } else {
        wcv_kernel<<<1728, 256, 0, stream>>>(w_conv, wth, wtl);
    }

    for (int i = 0; i < 8; i++){
        int D = DS[i]; double gd = GS[i];
        int ncell = D * D * D;
        int NC2 = 2 * ncell;
        hipMemsetAsync(vgrid, 0xFF, (size_t)NC2*sizeof(int), stream);
        if (ncell <= 2744)
            scatter_kernel<1><<<MTOT/256, 256, ncell*sizeof(int), stream>>>(p, pmin, vgrid, gcbuf, gd, D);
        else
            scatter_kernel<0><<<MTOT/256, 256, 0, stream>>>(p, pmin, vgrid, gcbuf, gd, D);

        const bool voxel = big && (NC2 < MTOT);

        if (voxel){
            int NC2pad = (NC2 + 31) & ~31;
            nbrv_kernel<<<(NC2pad + 255)/256, 256, 0, stream>>>(vgrid, nbrv, D, NC2, NC2pad);
            mlp_scale_kernel<<<(MTOT*32)/256, 256, 0, stream>>>(
                p, w1, b1, w_mlp + i*1024, b_mlp + i*32, h0h, h0l);
            vconv_kernel<<<NC2pad/32, 256, 0, stream>>>(
                h0h, h0l, wth + (size_t)(2*i)*27648, wtl + (size_t)(2*i)*27648,
                b_conv + (2*i)*32, nbrv, NC2pad, vv);
            combine_kernel<0><<<MTOT/128, 256, 0, stream>>>(
                h0h, h0l, wth + (size_t)(2*i)*27648, wtl + (size_t)(2*i)*27648,
                vv, gcbuf, D, nullptr, nullptr, h1h, h1l);
            vconv_kernel<<<NC2pad/32, 256, 0, stream>>>(
                h1h, h1l, wth + (size_t)(2*i+1)*27648, wtl + (size_t)(2*i+1)*27648,
                b_conv + (2*i+1)*32, nbrv, NC2pad, vv);
            combine_kernel<1><<<MTOT/128, 256, 0, stream>>>(
                h1h, h1l, wth + (size_t)(2*i+1)*27648, wtl + (size_t)(2*i+1)*27648,
                vv, gcbuf, D, h0h, h0l,
                vpl + (size_t)i*8388608, vpl + (size_t)i*8388608 + 4194304);
        } else {
            nbr_kernel<<<MTOT/256, 256, 0, stream>>>(gcbuf, vgrid, nbr, D);
            mlp_scale_kernel<<<(MTOT*32)/256, 256, 0, stream>>>(
                p, w1, b1, w_mlp + i*1024, b_mlp + i*32, h0h, h0l);
            if (big){
                conv4_kernel<0><<<MTOT/32, 256, 0, stream>>>(
                    h0h, h0l, wth + (size_t)(2*i)*27648, wtl + (size_t)(2*i)*27648,
                    b_conv + (2*i)*32, nbr, nullptr, nullptr, h1h, h1l);
                conv4_kernel<1><<<MTOT/32, 256, 0, stream>>>(
                    h1h, h1l, wth + (size_t)(2*i+1)*27648, wtl + (size_t)(2*i+1)*27648,
                    b_conv + (2*i+1)*32, nbr, h0h, h0l,
                    vpl + (size_t)i*8388608, vpl + (size_t)i*8388608 + 4194304);
            } else {
                conv_mfma_kernel<0><<<MTOT/64, 256, 0, stream>>>(
                    h0h, h0l, wth + (size_t)(2*i)*27648, wtl + (size_t)(2*i)*27648,
                    b_conv + (2*i)*32, nbr, nullptr, nullptr, nullptr, nullptr,
                    h1h, h1l, nullptr);
                if (i == 0)
                    conv_mfma_kernel<2><<<MTOT/64, 256, 0, stream>>>(
                        h1h, h1l, wth + (size_t)(2*i+1)*27648, wtl + (size_t)(2*i+1)*27648,
                        b_conv + (2*i+1)*32, nbr, h0h, h0l, w2 + i*32*128, b2,
                        nullptr, nullptr, out);
                else
                    conv_mfma_kernel<1><<<MTOT/64, 256, 0, stream>>>(
                        h1h, h1l, wth + (size_t)(2*i+1)*27648, wtl + (size_t)(2*i+1)*27648,
                        b_conv + (2*i+1)*32, nbr, h0h, h0l, w2 + i*32*128, nullptr,
                        nullptr, nullptr, out);
            }
        }
    }
    if (big)
        mlp2_kernel<<<MTOT/128, 256, 0, stream>>>(vpl, w2th, w2tl, b2, out);
}